// Round 4
// baseline (548.721 us; speedup 1.0000x reference)
//
#include <hip/hip_runtime.h>
#include <hip/hip_bf16.h>

#define NN 192
#define NBA 3
#define NH 8
#define ND 10
#define NE_ (NN*NN)          // 36864
#define OUTC 202             // 10 + 8*16 + 8*8

typedef unsigned int u32;
typedef unsigned short u16;

// ---- workspace layout (float-sized slots) ----
static const size_t OFF_FE0B  = 0;                        // [8][NE] uint2 (4xbf16)
static const size_t OFF_ET0B  = 589824;                   // [8][NE] u32 (exp(t),exp(.2t) bf16)
static const size_t OFF_FE1B  = OFF_ET0B + 294912;        // [8][NE] u32 (2xbf16)
static const size_t OFF_ET1B  = OFF_FE1B + 294912;        // [8][NE] u32
static const size_t OFF_EADJB = OFF_ET1B + 294912;        // [192][NE] u16 = 3538944 f-slots
static const size_t OFF_XH1   = OFF_EADJB + 3538944;      // [3][192][128] f32
static const size_t OFF_EINF  = OFF_XH1  + 73728;         // [3][192][192]
static const size_t OFF_PART  = OFF_EINF + 110592;        // [3][192][36][8][5]
static const size_t OFF_F2    = OFF_PART + 829440;        // [3][8][192][16]
static const size_t OFF_S2    = OFF_F2   + 73728;
static const size_t OFF_T2    = OFF_S2   + 4608;
static const size_t OFF_TE    = OFF_T2   + 4608;
static const size_t OFF_CS    = OFF_TE   + 4608;          // [3][192]
// total ~6.12M floats ~24.5 MB

__device__ __forceinline__ float blo(u32 u) { return __uint_as_float(u << 16); }
__device__ __forceinline__ float bhi(u32 u) { return __uint_as_float(u & 0xFFFF0000u); }
__device__ __forceinline__ u16 pbf(float x) {
    u32 u = __float_as_uint(x);
    return (u16)((u + 0x7FFFu + ((u >> 16) & 1u)) >> 16);   // RNE; finite inputs
}
__device__ __forceinline__ u32 pack2(float lo, float hi) {
    return (u32)pbf(lo) | ((u32)pbf(hi) << 16);
}

// ---------------- K0: attr-independent edge features (bf16-packed) ----------------
__global__ __launch_bounds__(256) void k_edge(
    const float* __restrict__ E,
    const float* __restrict__ we0, const float* __restrict__ aen0,
    const float* __restrict__ we1, const float* __restrict__ aen1,
    uint2* __restrict__ fe0, u32* __restrict__ et0,
    u32* __restrict__ fe1, u32* __restrict__ et1)
{
    __shared__ float w0s[96], a0s[32], w1s[512], a1s[16];
    int tid = threadIdx.x;
    for (int i = tid; i < 96;  i += 256) w0s[i] = we0[i];
    for (int i = tid; i < 32;  i += 256) a0s[i] = aen0[i];
    for (int i = tid; i < 512; i += 256) w1s[i] = we1[i];
    for (int i = tid; i < 16;  i += 256) a1s[i] = aen1[i];
    __syncthreads();
    int e = blockIdx.x * 256 + tid;
    float E0 = E[e], E1 = E[NE_ + e], E2 = E[2 * NE_ + e];
    float f0[32];
    #pragma unroll
    for (int h = 0; h < 8; h++) {
        #pragma unroll
        for (int f = 0; f < 4; f++)
            f0[h*4+f] = E0*w0s[h*12+f] + E1*w0s[h*12+4+f] + E2*w0s[h*12+8+f];
        float tv = f0[h*4]*a0s[h*4] + f0[h*4+1]*a0s[h*4+1]
                 + f0[h*4+2]*a0s[h*4+2] + f0[h*4+3]*a0s[h*4+3];
        et0[h*NE_ + e] = pack2(__expf(tv), __expf(0.2f*tv));
        fe0[h*NE_ + e] = make_uint2(pack2(f0[h*4], f0[h*4+1]), pack2(f0[h*4+2], f0[h*4+3]));
    }
    #pragma unroll
    for (int h = 0; h < 8; h++) {
        float a = 0.f, b = 0.f;
        #pragma unroll
        for (int d = 0; d < 32; d++) {
            a += f0[d] * w1s[(h*32+d)*2];
            b += f0[d] * w1s[(h*32+d)*2+1];
        }
        fe1[h*NE_ + e] = pack2(a, b);
        float tv = a*a1s[h*2] + b*a1s[h*2+1];
        et1[h*NE_ + e] = pack2(__expf(tv), __expf(0.2f*tv));
    }
}

// ---------------- K0b: eadj = bf16(exp(adj)) ----------------
__global__ __launch_bounds__(256) void k_eadj(
    const float* __restrict__ adj, uint2* __restrict__ eadjb)
{
    size_t i = (size_t)blockIdx.x * 256 + threadIdx.x;
    float4 v = *(const float4*)(adj + i * 4);
    eadjb[i] = make_uint2(pack2(__expf(v.x), __expf(v.y)),
                          pack2(__expf(v.z), __expf(v.w)));
}

// ---------------- K1: streaming e2n attention, 3 attrs fused, bf16 streams ----------------
// exp(lrelu(s+t)+adj) = max(es*et, es5*et5) * eadj.  Block: 8 waves = heads.
// Grid (S=36 splits x 48 n-tiles of TN=4). Each block stages its 4x1024 eadj chunk
// in LDS once (shared by all 8 heads); each lane owns 4 consecutive e.
template<int DIN, int F, int FE>
__global__ __launch_bounds__(512, 4) void k_att3(
    const float* __restrict__ Xh,    // [.][N][DIN], attr stride xstride (0 for L0)
    int xstride,
    const float* __restrict__ wn,    // [A][H][DIN][F]
    const float* __restrict__ aes,   // [H][F]
    const u32* __restrict__ etb,     // [H][NE] packed (et, et5)
    const u32* __restrict__ feb,     // [H][NE][FE/2] packed fe
    const u32* __restrict__ eadjb,   // [192][NE/2] packed exp(adj)
    float* __restrict__ part)        // [A][N][S][H][FE+1]
{
    constexpr int S = 36, TN = 4, NW = (DIN+63)/64, FEU = FE/2;
    int h = threadIdx.x >> 6;
    int lane = threadIdx.x & 63;
    int split = blockIdx.x;
    int n0 = blockIdx.y * TN;

    __shared__ u32 sh_ea[TN][512];   // 4 rows x 1024 bf16

    // issue eadj staging load early
    int r = threadIdx.x >> 7, c = threadIdx.x & 127;
    const u32* erow = eadjb + (size_t)(n0 + r) * (NE_/2) + split*512;
    uint4 stg = ((const uint4*)erow)[c];

    // prologue: es/es5 per (attr, node)
    float es[NBA][TN], es5[NBA][TN];
    #pragma unroll
    for (int a = 0; a < NBA; a++) {
        float wt[NW];
        #pragma unroll
        for (int i = 0; i < NW; i++) {
            int d = lane + 64*i;
            float w = 0.f;
            if (d < DIN) {
                const float* wp = wn + (((size_t)a*NH + h)*DIN + d)*F;
                #pragma unroll
                for (int f = 0; f < F; f++) w += wp[f] * aes[h*F+f];
            }
            wt[i] = w;
        }
        #pragma unroll
        for (int nt = 0; nt < TN; nt++) {
            float p = 0.f;
            #pragma unroll
            for (int i = 0; i < NW; i++) {
                int d = lane + 64*i;
                if (d < DIN) p += Xh[(size_t)a*xstride + (n0+nt)*DIN + d] * wt[i];
            }
            #pragma unroll
            for (int m = 1; m < 64; m <<= 1) p += __shfl_xor(p, m);
            es[a][nt]  = __expf(p);
            es5[a][nt] = __expf(0.2f*p);
        }
    }

    ((uint4*)sh_ea[r])[c] = stg;
    __syncthreads();

    float acc[NBA][TN][FE+1];
    #pragma unroll
    for (int a = 0; a < NBA; a++)
        #pragma unroll
        for (int nt = 0; nt < TN; nt++)
            #pragma unroll
            for (int j = 0; j <= FE; j++) acc[a][nt][j] = 0.f;

    const u32* etp = etb + (size_t)h * NE_ + split*1024;
    const u32* fep = feb + ((size_t)h * NE_ + (size_t)split*1024) * FEU;

    #pragma unroll 2
    for (int step = 0; step < 4; step++) {
        int el = step*64 + lane;              // 4-e group index within chunk
        uint4 etv = *(const uint4*)(etp + el*4);
        u32 ec[4] = {etv.x, etv.y, etv.z, etv.w};
        u32 fc[4*FEU];
        if constexpr (FEU == 2) {
            uint4 fa = *(const uint4*)(fep + el*8);
            uint4 fb = *(const uint4*)(fep + el*8 + 4);
            fc[0]=fa.x; fc[1]=fa.y; fc[2]=fa.z; fc[3]=fa.w;
            fc[4]=fb.x; fc[5]=fb.y; fc[6]=fb.z; fc[7]=fb.w;
        } else {
            uint4 fa = *(const uint4*)(fep + el*4);
            fc[0]=fa.x; fc[1]=fa.y; fc[2]=fa.z; fc[3]=fa.w;
        }
        uint2 eav[TN];
        #pragma unroll
        for (int nt = 0; nt < TN; nt++)
            eav[nt] = *(const uint2*)(&sh_ea[nt][el*2]);

        #pragma unroll
        for (int j = 0; j < 4; j++) {         // 4 e's per lane
            float eT  = blo(ec[j]);
            float eT5 = bhi(ec[j]);
            float fv[FE];
            if constexpr (FEU == 2) {
                fv[0] = blo(fc[2*j]);   fv[1] = bhi(fc[2*j]);
                fv[2] = blo(fc[2*j+1]); fv[3] = bhi(fc[2*j+1]);
            } else {
                fv[0] = blo(fc[j]);     fv[1] = bhi(fc[j]);
            }
            #pragma unroll
            for (int nt = 0; nt < TN; nt++) {
                u32 eu = (j < 2) ? eav[nt].x : eav[nt].y;
                float ea = (j & 1) ? bhi(eu) : blo(eu);
                float eta = eT * ea;
                float etbv = eT5 * ea;
                #pragma unroll
                for (int a = 0; a < NBA; a++) {
                    float w = fmaxf(es[a][nt]*eta, es5[a][nt]*etbv);
                    acc[a][nt][FE] += w;
                    #pragma unroll
                    for (int f = 0; f < FE; f++) acc[a][nt][f] += w * fv[f];
                }
            }
        }
    }

    #pragma unroll
    for (int a = 0; a < NBA; a++)
        #pragma unroll
        for (int nt = 0; nt < TN; nt++)
            #pragma unroll
            for (int j = 0; j <= FE; j++) {
                float v = acc[a][nt][j];
                #pragma unroll
                for (int m = 1; m < 64; m <<= 1) v += __shfl_xor(v, m);
                acc[a][nt][j] = v;
            }
    if (lane == 0) {
        #pragma unroll
        for (int a = 0; a < NBA; a++)
            #pragma unroll
            for (int nt = 0; nt < TN; nt++)
                #pragma unroll
                for (int j = 0; j <= FE; j++)
                    part[((((size_t)a*NN + n0+nt)*S + split)*NH + h)*(FE+1) + j] = acc[a][nt][j];
    }
}

// ---------------- K2: combine partials; f2, s2, t2 (grid.y = attr) ----------------
template<int DIN, int F, int FE>
__global__ __launch_bounds__(256) void k_mid(
    const float* __restrict__ Xh, int xstride,
    const float* __restrict__ wn,   // [A][H][DIN][F]
    const float* __restrict__ be,   // [H][FE]
    const float* __restrict__ wct,  // [H][F+FE][F]
    const float* __restrict__ bct,  // [H][F]
    const float* __restrict__ asf,  // [A][H][F]
    const float* __restrict__ anf,  // [A][H][F]
    const float* __restrict__ part, // [A][N][S][H][FE+1]
    float* __restrict__ f2, float* __restrict__ s2, float* __restrict__ t2)
{
    constexpr int S = 36, DCT = F + FE;
    int n = blockIdx.x, attr = blockIdx.y;
    int h = threadIdx.x >> 5, lane = threadIdx.x & 31;
    const float* Xp = Xh + (size_t)attr*xstride;
    const float* wnp = wn + (size_t)attr*NH*DIN*F;
    float* f2p = f2 + (size_t)attr*NH*NN*16;
    float v = 0.f;
    if (lane <= FE) {
        #pragma unroll
        for (int s = 0; s < S; s++)
            v += part[((((size_t)attr*NN + n)*S + s)*NH + h)*(FE+1) + lane];
    }
    float den = __shfl(v, FE, 32);
    float nfe = (lane < FE) ? v/den + be[h*FE+lane] : 0.f;
    float fv = 0.f;
    if (lane < F) {
        for (int d = 0; d < DIN; d++) fv += Xp[n*DIN+d] * wnp[(h*DIN+d)*F+lane];
    }
    __shared__ float c[NH][DCT];
    if (lane < F)  c[h][lane]     = fv;
    if (lane < FE) c[h][F + lane] = nfe;
    __syncthreads();
    float f2v = 0.f;
    if (lane < F) {
        f2v = bct[h*F+lane];
        #pragma unroll
        for (int d = 0; d < DCT; d++) f2v += c[h][d] * wct[(h*DCT+d)*F+lane];
        f2p[((size_t)h*NN + n)*16 + lane] = f2v;
    }
    float s2p = (lane < F) ? f2v * asf[attr*NH*F + h*F+lane] : 0.f;
    float t2p = (lane < F) ? f2v * anf[attr*NH*F + h*F+lane] : 0.f;
    #pragma unroll
    for (int m = 1; m < 32; m <<= 1) { s2p += __shfl_xor(s2p, m); t2p += __shfl_xor(t2p, m); }
    if (lane == 0) { s2[attr*NH*NN + h*NN+n] = s2p; t2[attr*NH*NN + h*NN+n] = t2p; }
}

// ---------------- K3: tE[h,k] = sum_m t2[h,m]*Einfo[m,k]; colsum (grid.y=attr) ----------------
__global__ __launch_bounds__(192) void k_te(
    const float* __restrict__ Einfo, size_t estride,
    const float* __restrict__ t2,
    float* __restrict__ tE, float* __restrict__ cs)
{
    int h = blockIdx.x, attr = blockIdx.y, k = threadIdx.x;
    const float* Ep = Einfo + (size_t)attr*estride;
    float a = 0.f, c = 0.f;
    for (int m = 0; m < NN; m++) {
        float ev = Ep[m*NN + k];
        a += t2[attr*NH*NN + h*NN + m] * ev;
        c += ev;
    }
    tE[attr*NH*NN + h*NN + k] = a;
    if (h == 0) cs[attr*NN + k] = c;
}

// ---------------- K4: att2 rows, nf, outputs (grid.y = attr) ----------------
template<int F, int LAYER>
__global__ __launch_bounds__(256) void k_out(
    const float* __restrict__ A,    // [A][N][N]
    const float* __restrict__ s2, const float* __restrict__ tE,
    const float* __restrict__ cs, const float* __restrict__ f2,
    const float* __restrict__ bn,   // [A][H][F]
    const float* __restrict__ X,
    float* __restrict__ out,
    float* __restrict__ xh1, float* __restrict__ einfo)
{
    int n = blockIdx.x, attr = blockIdx.y;
    int h = threadIdx.x >> 5, lane = threadIdx.x & 31;
    const float* Aattr = A + (size_t)attr*NE_;
    const float* f2p = f2 + (size_t)attr*NH*NN*16;
    float s2h = s2[attr*NH*NN + h*NN + n];
    float z[6];
    #pragma unroll
    for (int c6 = 0; c6 < 6; c6++) {
        int k = lane + 32*c6;
        float d2v = s2h * cs[attr*NN + k] + tE[attr*NH*NN + h*NN + k];
        z[c6] = fmaxf(d2v, 0.2f*d2v) + Aattr[n*NN + k];
    }
    float mx = z[0];
    #pragma unroll
    for (int c6 = 1; c6 < 6; c6++) mx = fmaxf(mx, z[c6]);
    #pragma unroll
    for (int m = 1; m < 32; m <<= 1) mx = fmaxf(mx, __shfl_xor(mx, m));
    float w[6], den = 0.f;
    #pragma unroll
    for (int c6 = 0; c6 < 6; c6++) { w[c6] = __expf(z[c6] - mx); den += w[c6]; }
    #pragma unroll
    for (int m = 1; m < 32; m <<= 1) den += __shfl_xor(den, m);
    __shared__ float attL[NH][NN];
    #pragma unroll
    for (int c6 = 0; c6 < 6; c6++) attL[h][lane + 32*c6] = w[c6];
    __syncthreads();
    if (lane < F) {
        float r = 0.f;
        for (int k = 0; k < NN; k++) r += attL[h][k] * f2p[((size_t)h*NN + k)*16 + lane];
        r = r/den + bn[attr*NH*F + h*F + lane];
        r = r > 0.f ? r : __expf(r) - 1.f;   // elu
        out[((size_t)n*NBA + attr)*OUTC + (LAYER == 0 ? 10 : 138) + h*F + lane] = r;
        if (LAYER == 0) xh1[(size_t)attr*NN*128 + n*128 + h*16 + lane] = r;
    }
    if (LAYER == 0 && h == 7) {
        #pragma unroll
        for (int c6 = 0; c6 < 6; c6++)
            einfo[(size_t)attr*NE_ + n*NN + lane + 32*c6] = w[c6] / den;
    }
    if (LAYER == 0 && h == 0 && lane < ND)
        out[((size_t)n*NBA + attr)*OUTC + lane] = X[n*ND + lane];
}

extern "C" void kernel_launch(void* const* d_in, const int* in_sizes, int n_in,
                              void* d_out, int out_size, void* d_ws, size_t ws_size,
                              hipStream_t stream) {
    const float* X    = (const float*)d_in[0];
    const float* A    = (const float*)d_in[1];
    const float* E    = (const float*)d_in[2];
    const float* adj  = (const float*)d_in[3];
    const float* w_n0 = (const float*)d_in[4];
    const float* b_n0 = (const float*)d_in[5];
    const float* as0  = (const float*)d_in[6];
    const float* an0  = (const float*)d_in[7];
    const float* w_n1 = (const float*)d_in[8];
    const float* b_n1 = (const float*)d_in[9];
    const float* as1  = (const float*)d_in[10];
    const float* an1  = (const float*)d_in[11];
    const float* w_e0 = (const float*)d_in[12];
    const float* b_e0 = (const float*)d_in[13];
    const float* w_ct0= (const float*)d_in[14];
    const float* b_ct0= (const float*)d_in[15];
    const float* aes0 = (const float*)d_in[16];
    const float* aen0 = (const float*)d_in[17];
    const float* w_e1 = (const float*)d_in[18];
    const float* b_e1 = (const float*)d_in[19];
    const float* w_ct1= (const float*)d_in[20];
    const float* b_ct1= (const float*)d_in[21];
    const float* aes1 = (const float*)d_in[22];
    const float* aen1 = (const float*)d_in[23];

    float* w      = (float*)d_ws;
    uint2* fe0b   = (uint2*)(w + OFF_FE0B);
    u32*   et0b   = (u32*)(w + OFF_ET0B);
    u32*   fe1b   = (u32*)(w + OFF_FE1B);
    u32*   et1b   = (u32*)(w + OFF_ET1B);
    u32*   eadjb  = (u32*)(w + OFF_EADJB);
    float* xh1    = w + OFF_XH1;
    float* einfo  = w + OFF_EINF;
    float* part   = w + OFF_PART;
    float* f2     = w + OFF_F2;
    float* s2     = w + OFF_S2;
    float* t2     = w + OFF_T2;
    float* tE     = w + OFF_TE;
    float* cs     = w + OFF_CS;
    float* out    = (float*)d_out;

    k_edge<<<dim3(NE_/256), dim3(256), 0, stream>>>(E, w_e0, aen0, w_e1, aen1,
                                                    fe0b, et0b, fe1b, et1b);
    k_eadj<<<dim3((NN*NE_)/1024), dim3(256), 0, stream>>>(adj, (uint2*)eadjb);

    // ---- layer 0 ----
    k_att3<10,16,4><<<dim3(36,48), dim3(512), 0, stream>>>(
        X, 0, w_n0, aes0, et0b, (const u32*)fe0b, eadjb, part);
    k_mid<10,16,4><<<dim3(NN,NBA), dim3(256), 0, stream>>>(
        X, 0, w_n0, b_e0, w_ct0, b_ct0, as0, an0, part, f2, s2, t2);
    k_te<<<dim3(8,NBA), dim3(192), 0, stream>>>(E, (size_t)NE_, t2, tE, cs);
    k_out<16,0><<<dim3(NN,NBA), dim3(256), 0, stream>>>(
        A, s2, tE, cs, f2, b_n0, X, out, xh1, einfo);

    // ---- layer 1 ----
    k_att3<128,8,2><<<dim3(36,48), dim3(512), 0, stream>>>(
        xh1, NN*128, w_n1, aes1, et1b, fe1b, eadjb, part);
    k_mid<128,8,2><<<dim3(NN,NBA), dim3(256), 0, stream>>>(
        xh1, NN*128, w_n1, b_e1, w_ct1, b_ct1, as1, an1, part, f2, s2, t2);
    k_te<<<dim3(8,NBA), dim3(192), 0, stream>>>(einfo, (size_t)NE_, t2, tE, cs);
    k_out<8,1><<<dim3(NN,NBA), dim3(256), 0, stream>>>(
        A, s2, tE, cs, f2, b_n1, X, out, xh1, einfo);
}

// Round 5
// 254.377 us; speedup vs baseline: 2.1571x; 2.1571x over previous
//
#include <hip/hip_runtime.h>
#include <hip/hip_bf16.h>

#define NN 192
#define NBA 3
#define NH 8
#define ND 10
#define NE_ (NN*NN)          // 36864
#define OUTC 202             // 10 + 8*16 + 8*8

typedef unsigned int u32;
typedef unsigned short u16;

// ---- workspace layout (float-sized slots) ----
static const size_t OFF_FE0B  = 0;                        // [8][NE] uint2 (4xbf16)
static const size_t OFF_ET0B  = 589824;                   // [8][NE] u32 (exp(t),exp(.2t) bf16)
static const size_t OFF_FE1B  = OFF_ET0B + 294912;        // [8][NE] u32 (2xbf16)
static const size_t OFF_ET1B  = OFF_FE1B + 294912;        // [8][NE] u32
static const size_t OFF_EADJB = OFF_ET1B + 294912;        // [192][NE] u16 = 3538944 f-slots
static const size_t OFF_XH1   = OFF_EADJB + 3538944;      // [3][192][128] f32
static const size_t OFF_EINF  = OFF_XH1  + 73728;         // [3][192][192]
static const size_t OFF_PART  = OFF_EINF + 110592;        // [3][192][36][8][5]
static const size_t OFF_F2    = OFF_PART + 829440;        // [3][8][192][16]
static const size_t OFF_S2    = OFF_F2   + 73728;
static const size_t OFF_T2    = OFF_S2   + 4608;
static const size_t OFF_TE    = OFF_T2   + 4608;
static const size_t OFF_CS    = OFF_TE   + 4608;          // [3][192]
// total ~6.12M floats ~24.5 MB

__device__ __forceinline__ float blo(u32 u) { return __uint_as_float(u << 16); }
__device__ __forceinline__ float bhi(u32 u) { return __uint_as_float(u & 0xFFFF0000u); }
__device__ __forceinline__ u16 pbf(float x) {
    u32 u = __float_as_uint(x);
    return (u16)((u + 0x7FFFu + ((u >> 16) & 1u)) >> 16);   // RNE; finite inputs
}
__device__ __forceinline__ u32 pack2(float lo, float hi) {
    return (u32)pbf(lo) | ((u32)pbf(hi) << 16);
}

// ---------------- K0: attr-independent edge features (bf16-packed) ----------------
__global__ __launch_bounds__(256) void k_edge(
    const float* __restrict__ E,
    const float* __restrict__ we0, const float* __restrict__ aen0,
    const float* __restrict__ we1, const float* __restrict__ aen1,
    uint2* __restrict__ fe0, u32* __restrict__ et0,
    u32* __restrict__ fe1, u32* __restrict__ et1)
{
    __shared__ float w0s[96], a0s[32], w1s[512], a1s[16];
    int tid = threadIdx.x;
    for (int i = tid; i < 96;  i += 256) w0s[i] = we0[i];
    for (int i = tid; i < 32;  i += 256) a0s[i] = aen0[i];
    for (int i = tid; i < 512; i += 256) w1s[i] = we1[i];
    for (int i = tid; i < 16;  i += 256) a1s[i] = aen1[i];
    __syncthreads();
    int e = blockIdx.x * 256 + tid;
    float E0 = E[e], E1 = E[NE_ + e], E2 = E[2 * NE_ + e];
    float f0[32];
    #pragma unroll
    for (int h = 0; h < 8; h++) {
        #pragma unroll
        for (int f = 0; f < 4; f++)
            f0[h*4+f] = E0*w0s[h*12+f] + E1*w0s[h*12+4+f] + E2*w0s[h*12+8+f];
        float tv = f0[h*4]*a0s[h*4] + f0[h*4+1]*a0s[h*4+1]
                 + f0[h*4+2]*a0s[h*4+2] + f0[h*4+3]*a0s[h*4+3];
        et0[h*NE_ + e] = pack2(__expf(tv), __expf(0.2f*tv));
        fe0[h*NE_ + e] = make_uint2(pack2(f0[h*4], f0[h*4+1]), pack2(f0[h*4+2], f0[h*4+3]));
    }
    #pragma unroll
    for (int h = 0; h < 8; h++) {
        float a = 0.f, b = 0.f;
        #pragma unroll
        for (int d = 0; d < 32; d++) {
            a += f0[d] * w1s[(h*32+d)*2];
            b += f0[d] * w1s[(h*32+d)*2+1];
        }
        fe1[h*NE_ + e] = pack2(a, b);
        float tv = a*a1s[h*2] + b*a1s[h*2+1];
        et1[h*NE_ + e] = pack2(__expf(tv), __expf(0.2f*tv));
    }
}

// ---------------- K0b: eadj = bf16(exp(adj)) ----------------
__global__ __launch_bounds__(256) void k_eadj(
    const float* __restrict__ adj, uint2* __restrict__ eadjb)
{
    size_t i = (size_t)blockIdx.x * 256 + threadIdx.x;
    float4 v = *(const float4*)(adj + i * 4);
    eadjb[i] = make_uint2(pack2(__expf(v.x), __expf(v.y)),
                          pack2(__expf(v.z), __expf(v.w)));
}

// ---------------- K1: streaming e2n attention, 3 attrs fused, bf16 streams ----------------
// exp(lrelu(s+t)+adj) = max(es*et, es5*et5) * eadj.  Block: 8 waves = heads.
// Grid (S=36 splits x 48 n-tiles of TN=4). Each block stages its 4x1024 eadj chunk
// in LDS once (shared by all 8 heads); each lane owns 4 consecutive e.
// launch_bounds (512,2): 128 VGPR cap — (512,4) capped at 64 and spilled acc to
// scratch (R4: 897 MB WRITE_SIZE/dispatch, 344 us).
template<int DIN, int F, int FE>
__global__ __launch_bounds__(512, 2) void k_att3(
    const float* __restrict__ Xh,    // [.][N][DIN], attr stride xstride (0 for L0)
    int xstride,
    const float* __restrict__ wn,    // [A][H][DIN][F]
    const float* __restrict__ aes,   // [H][F]
    const u32* __restrict__ etb,     // [H][NE] packed (et, et5)
    const u32* __restrict__ feb,     // [H][NE][FE/2] packed fe
    const u32* __restrict__ eadjb,   // [192][NE/2] packed exp(adj)
    float* __restrict__ part)        // [A][N][S][H][FE+1]
{
    constexpr int S = 36, TN = 4, NW = (DIN+63)/64, FEU = FE/2;
    int h = threadIdx.x >> 6;
    int lane = threadIdx.x & 63;
    int split = blockIdx.x;
    int n0 = blockIdx.y * TN;

    __shared__ u32 sh_ea[TN][512];   // 4 rows x 1024 bf16

    // issue eadj staging load early
    int r = threadIdx.x >> 7, c = threadIdx.x & 127;
    const u32* erow = eadjb + (size_t)(n0 + r) * (NE_/2) + split*512;
    uint4 stg = ((const uint4*)erow)[c];

    // prologue: es/es5 per (attr, node)
    float es[NBA][TN], es5[NBA][TN];
    #pragma unroll
    for (int a = 0; a < NBA; a++) {
        float wt[NW];
        #pragma unroll
        for (int i = 0; i < NW; i++) {
            int d = lane + 64*i;
            float w = 0.f;
            if (d < DIN) {
                const float* wp = wn + (((size_t)a*NH + h)*DIN + d)*F;
                #pragma unroll
                for (int f = 0; f < F; f++) w += wp[f] * aes[h*F+f];
            }
            wt[i] = w;
        }
        #pragma unroll
        for (int nt = 0; nt < TN; nt++) {
            float p = 0.f;
            #pragma unroll
            for (int i = 0; i < NW; i++) {
                int d = lane + 64*i;
                if (d < DIN) p += Xh[(size_t)a*xstride + (n0+nt)*DIN + d] * wt[i];
            }
            #pragma unroll
            for (int m = 1; m < 64; m <<= 1) p += __shfl_xor(p, m);
            es[a][nt]  = __expf(p);
            es5[a][nt] = __expf(0.2f*p);
        }
    }

    ((uint4*)sh_ea[r])[c] = stg;
    __syncthreads();

    float acc[NBA][TN][FE+1];
    #pragma unroll
    for (int a = 0; a < NBA; a++)
        #pragma unroll
        for (int nt = 0; nt < TN; nt++)
            #pragma unroll
            for (int j = 0; j <= FE; j++) acc[a][nt][j] = 0.f;

    const u32* etp = etb + (size_t)h * NE_ + split*1024;
    const u32* fep = feb + ((size_t)h * NE_ + (size_t)split*1024) * FEU;

    #pragma unroll 2
    for (int step = 0; step < 4; step++) {
        int el = step*64 + lane;              // 4-e group index within chunk
        uint4 etv = *(const uint4*)(etp + el*4);
        u32 ec[4] = {etv.x, etv.y, etv.z, etv.w};
        u32 fc[4*FEU];
        if constexpr (FEU == 2) {
            uint4 fa = *(const uint4*)(fep + el*8);
            uint4 fb = *(const uint4*)(fep + el*8 + 4);
            fc[0]=fa.x; fc[1]=fa.y; fc[2]=fa.z; fc[3]=fa.w;
            fc[4]=fb.x; fc[5]=fb.y; fc[6]=fb.z; fc[7]=fb.w;
        } else {
            uint4 fa = *(const uint4*)(fep + el*4);
            fc[0]=fa.x; fc[1]=fa.y; fc[2]=fa.z; fc[3]=fa.w;
        }
        uint2 eav[TN];
        #pragma unroll
        for (int nt = 0; nt < TN; nt++)
            eav[nt] = *(const uint2*)(&sh_ea[nt][el*2]);

        #pragma unroll
        for (int j = 0; j < 4; j++) {         // 4 e's per lane
            float eT  = blo(ec[j]);
            float eT5 = bhi(ec[j]);
            float fv[FE];
            if constexpr (FEU == 2) {
                fv[0] = blo(fc[2*j]);   fv[1] = bhi(fc[2*j]);
                fv[2] = blo(fc[2*j+1]); fv[3] = bhi(fc[2*j+1]);
            } else {
                fv[0] = blo(fc[j]);     fv[1] = bhi(fc[j]);
            }
            #pragma unroll
            for (int nt = 0; nt < TN; nt++) {
                u32 eu = (j < 2) ? eav[nt].x : eav[nt].y;
                float ea = (j & 1) ? bhi(eu) : blo(eu);
                float eta = eT * ea;
                float etbv = eT5 * ea;
                #pragma unroll
                for (int a = 0; a < NBA; a++) {
                    float w = fmaxf(es[a][nt]*eta, es5[a][nt]*etbv);
                    acc[a][nt][FE] += w;
                    #pragma unroll
                    for (int f = 0; f < FE; f++) acc[a][nt][f] += w * fv[f];
                }
            }
        }
    }

    #pragma unroll
    for (int a = 0; a < NBA; a++)
        #pragma unroll
        for (int nt = 0; nt < TN; nt++)
            #pragma unroll
            for (int j = 0; j <= FE; j++) {
                float v = acc[a][nt][j];
                #pragma unroll
                for (int m = 1; m < 64; m <<= 1) v += __shfl_xor(v, m);
                acc[a][nt][j] = v;
            }
    if (lane == 0) {
        #pragma unroll
        for (int a = 0; a < NBA; a++)
            #pragma unroll
            for (int nt = 0; nt < TN; nt++)
                #pragma unroll
                for (int j = 0; j <= FE; j++)
                    part[((((size_t)a*NN + n0+nt)*S + split)*NH + h)*(FE+1) + j] = acc[a][nt][j];
    }
}

// ---------------- K2: combine partials; f2, s2, t2 (grid.y = attr) ----------------
template<int DIN, int F, int FE>
__global__ __launch_bounds__(256) void k_mid(
    const float* __restrict__ Xh, int xstride,
    const float* __restrict__ wn,   // [A][H][DIN][F]
    const float* __restrict__ be,   // [H][FE]
    const float* __restrict__ wct,  // [H][F+FE][F]
    const float* __restrict__ bct,  // [H][F]
    const float* __restrict__ asf,  // [A][H][F]
    const float* __restrict__ anf,  // [A][H][F]
    const float* __restrict__ part, // [A][N][S][H][FE+1]
    float* __restrict__ f2, float* __restrict__ s2, float* __restrict__ t2)
{
    constexpr int S = 36, DCT = F + FE;
    int n = blockIdx.x, attr = blockIdx.y;
    int h = threadIdx.x >> 5, lane = threadIdx.x & 31;
    const float* Xp = Xh + (size_t)attr*xstride;
    const float* wnp = wn + (size_t)attr*NH*DIN*F;
    float* f2p = f2 + (size_t)attr*NH*NN*16;
    float v = 0.f;
    if (lane <= FE) {
        #pragma unroll
        for (int s = 0; s < S; s++)
            v += part[((((size_t)attr*NN + n)*S + s)*NH + h)*(FE+1) + lane];
    }
    float den = __shfl(v, FE, 32);
    float nfe = (lane < FE) ? v/den + be[h*FE+lane] : 0.f;
    float fv = 0.f;
    if (lane < F) {
        for (int d = 0; d < DIN; d++) fv += Xp[n*DIN+d] * wnp[(h*DIN+d)*F+lane];
    }
    __shared__ float c[NH][DCT];
    if (lane < F)  c[h][lane]     = fv;
    if (lane < FE) c[h][F + lane] = nfe;
    __syncthreads();
    float f2v = 0.f;
    if (lane < F) {
        f2v = bct[h*F+lane];
        #pragma unroll
        for (int d = 0; d < DCT; d++) f2v += c[h][d] * wct[(h*DCT+d)*F+lane];
        f2p[((size_t)h*NN + n)*16 + lane] = f2v;
    }
    float s2p = (lane < F) ? f2v * asf[attr*NH*F + h*F+lane] : 0.f;
    float t2p = (lane < F) ? f2v * anf[attr*NH*F + h*F+lane] : 0.f;
    #pragma unroll
    for (int m = 1; m < 32; m <<= 1) { s2p += __shfl_xor(s2p, m); t2p += __shfl_xor(t2p, m); }
    if (lane == 0) { s2[attr*NH*NN + h*NN+n] = s2p; t2[attr*NH*NN + h*NN+n] = t2p; }
}

// ---------------- K3: tE[h,k] = sum_m t2[h,m]*Einfo[m,k]; colsum (grid.y=attr) ----------------
__global__ __launch_bounds__(192) void k_te(
    const float* __restrict__ Einfo, size_t estride,
    const float* __restrict__ t2,
    float* __restrict__ tE, float* __restrict__ cs)
{
    int h = blockIdx.x, attr = blockIdx.y, k = threadIdx.x;
    const float* Ep = Einfo + (size_t)attr*estride;
    float a = 0.f, c = 0.f;
    for (int m = 0; m < NN; m++) {
        float ev = Ep[m*NN + k];
        a += t2[attr*NH*NN + h*NN + m] * ev;
        c += ev;
    }
    tE[attr*NH*NN + h*NN + k] = a;
    if (h == 0) cs[attr*NN + k] = c;
}

// ---------------- K4: att2 rows, nf, outputs (grid.y = attr) ----------------
template<int F, int LAYER>
__global__ __launch_bounds__(256) void k_out(
    const float* __restrict__ A,    // [A][N][N]
    const float* __restrict__ s2, const float* __restrict__ tE,
    const float* __restrict__ cs, const float* __restrict__ f2,
    const float* __restrict__ bn,   // [A][H][F]
    const float* __restrict__ X,
    float* __restrict__ out,
    float* __restrict__ xh1, float* __restrict__ einfo)
{
    int n = blockIdx.x, attr = blockIdx.y;
    int h = threadIdx.x >> 5, lane = threadIdx.x & 31;
    const float* Aattr = A + (size_t)attr*NE_;
    const float* f2p = f2 + (size_t)attr*NH*NN*16;
    float s2h = s2[attr*NH*NN + h*NN + n];
    float z[6];
    #pragma unroll
    for (int c6 = 0; c6 < 6; c6++) {
        int k = lane + 32*c6;
        float d2v = s2h * cs[attr*NN + k] + tE[attr*NH*NN + h*NN + k];
        z[c6] = fmaxf(d2v, 0.2f*d2v) + Aattr[n*NN + k];
    }
    float mx = z[0];
    #pragma unroll
    for (int c6 = 1; c6 < 6; c6++) mx = fmaxf(mx, z[c6]);
    #pragma unroll
    for (int m = 1; m < 32; m <<= 1) mx = fmaxf(mx, __shfl_xor(mx, m));
    float w[6], den = 0.f;
    #pragma unroll
    for (int c6 = 0; c6 < 6; c6++) { w[c6] = __expf(z[c6] - mx); den += w[c6]; }
    #pragma unroll
    for (int m = 1; m < 32; m <<= 1) den += __shfl_xor(den, m);
    __shared__ float attL[NH][NN];
    #pragma unroll
    for (int c6 = 0; c6 < 6; c6++) attL[h][lane + 32*c6] = w[c6];
    __syncthreads();
    if (lane < F) {
        float r = 0.f;
        for (int k = 0; k < NN; k++) r += attL[h][k] * f2p[((size_t)h*NN + k)*16 + lane];
        r = r/den + bn[attr*NH*F + h*F + lane];
        r = r > 0.f ? r : __expf(r) - 1.f;   // elu
        out[((size_t)n*NBA + attr)*OUTC + (LAYER == 0 ? 10 : 138) + h*F + lane] = r;
        if (LAYER == 0) xh1[(size_t)attr*NN*128 + n*128 + h*16 + lane] = r;
    }
    if (LAYER == 0 && h == 7) {
        #pragma unroll
        for (int c6 = 0; c6 < 6; c6++)
            einfo[(size_t)attr*NE_ + n*NN + lane + 32*c6] = w[c6] / den;
    }
    if (LAYER == 0 && h == 0 && lane < ND)
        out[((size_t)n*NBA + attr)*OUTC + lane] = X[n*ND + lane];
}

extern "C" void kernel_launch(void* const* d_in, const int* in_sizes, int n_in,
                              void* d_out, int out_size, void* d_ws, size_t ws_size,
                              hipStream_t stream) {
    const float* X    = (const float*)d_in[0];
    const float* A    = (const float*)d_in[1];
    const float* E    = (const float*)d_in[2];
    const float* adj  = (const float*)d_in[3];
    const float* w_n0 = (const float*)d_in[4];
    const float* b_n0 = (const float*)d_in[5];
    const float* as0  = (const float*)d_in[6];
    const float* an0  = (const float*)d_in[7];
    const float* w_n1 = (const float*)d_in[8];
    const float* b_n1 = (const float*)d_in[9];
    const float* as1  = (const float*)d_in[10];
    const float* an1  = (const float*)d_in[11];
    const float* w_e0 = (const float*)d_in[12];
    const float* b_e0 = (const float*)d_in[13];
    const float* w_ct0= (const float*)d_in[14];
    const float* b_ct0= (const float*)d_in[15];
    const float* aes0 = (const float*)d_in[16];
    const float* aen0 = (const float*)d_in[17];
    const float* w_e1 = (const float*)d_in[18];
    const float* b_e1 = (const float*)d_in[19];
    const float* w_ct1= (const float*)d_in[20];
    const float* b_ct1= (const float*)d_in[21];
    const float* aes1 = (const float*)d_in[22];
    const float* aen1 = (const float*)d_in[23];

    float* w      = (float*)d_ws;
    uint2* fe0b   = (uint2*)(w + OFF_FE0B);
    u32*   et0b   = (u32*)(w + OFF_ET0B);
    u32*   fe1b   = (u32*)(w + OFF_FE1B);
    u32*   et1b   = (u32*)(w + OFF_ET1B);
    u32*   eadjb  = (u32*)(w + OFF_EADJB);
    float* xh1    = w + OFF_XH1;
    float* einfo  = w + OFF_EINF;
    float* part   = w + OFF_PART;
    float* f2     = w + OFF_F2;
    float* s2     = w + OFF_S2;
    float* t2     = w + OFF_T2;
    float* tE     = w + OFF_TE;
    float* cs     = w + OFF_CS;
    float* out    = (float*)d_out;

    k_edge<<<dim3(NE_/256), dim3(256), 0, stream>>>(E, w_e0, aen0, w_e1, aen1,
                                                    fe0b, et0b, fe1b, et1b);
    k_eadj<<<dim3((NN*NE_)/1024), dim3(256), 0, stream>>>(adj, (uint2*)eadjb);

    // ---- layer 0 ----
    k_att3<10,16,4><<<dim3(36,48), dim3(512), 0, stream>>>(
        X, 0, w_n0, aes0, et0b, (const u32*)fe0b, eadjb, part);
    k_mid<10,16,4><<<dim3(NN,NBA), dim3(256), 0, stream>>>(
        X, 0, w_n0, b_e0, w_ct0, b_ct0, as0, an0, part, f2, s2, t2);
    k_te<<<dim3(8,NBA), dim3(192), 0, stream>>>(E, (size_t)NE_, t2, tE, cs);
    k_out<16,0><<<dim3(NN,NBA), dim3(256), 0, stream>>>(
        A, s2, tE, cs, f2, b_n0, X, out, xh1, einfo);

    // ---- layer 1 ----
    k_att3<128,8,2><<<dim3(36,48), dim3(512), 0, stream>>>(
        xh1, NN*128, w_n1, aes1, et1b, fe1b, eadjb, part);
    k_mid<128,8,2><<<dim3(NN,NBA), dim3(256), 0, stream>>>(
        xh1, NN*128, w_n1, b_e1, w_ct1, b_ct1, as1, an1, part, f2, s2, t2);
    k_te<<<dim3(8,NBA), dim3(192), 0, stream>>>(einfo, (size_t)NE_, t2, tE, cs);
    k_out<8,1><<<dim3(NN,NBA), dim3(256), 0, stream>>>(
        A, s2, tE, cs, f2, b_n1, X, out, xh1, einfo);
}

// Round 6
// 191.332 us; speedup vs baseline: 2.8679x; 1.3295x over previous
//
#include <hip/hip_runtime.h>
#include <hip/hip_bf16.h>

#define NN 192
#define NBA 3
#define NH 8
#define ND 10
#define NE_ (NN*NN)          // 36864
#define OUTC 202             // 10 + 8*16 + 8*8

typedef unsigned int u32;
typedef unsigned short u16;

// ---- workspace layout (float-sized slots) ----
static const size_t OFF_FE0B  = 0;                        // [8][NE] uint2 (4xbf16)
static const size_t OFF_ET0B  = 589824;                   // [8][NE] u32 (exp(t),exp(.2t) bf16)
static const size_t OFF_FE1B  = OFF_ET0B + 294912;        // [8][NE] u32 (2xbf16)
static const size_t OFF_ET1B  = OFF_FE1B + 294912;        // [8][NE] u32
static const size_t OFF_EADJP = OFF_ET1B + 294912;        // [NE/2][192] u32 (exp adj pair, transposed)
static const size_t OFF_XH1   = OFF_EADJP + 3538944;      // [3][192][128] f32
static const size_t OFF_EINF  = OFF_XH1  + 73728;         // [3][192][192]
static const size_t OFF_ES    = OFF_EINF + 110592;        // [3][8][192]
static const size_t OFF_ES5   = OFF_ES   + 4608;
static const size_t OFF_PART  = OFF_ES5  + 4608;          // [3][192][8][5][64]
static const size_t OFF_F2    = OFF_PART + 1474560;       // [3][8][192][16]
static const size_t OFF_S2    = OFF_F2   + 73728;
static const size_t OFF_T2    = OFF_S2   + 4608;
static const size_t OFF_TE    = OFF_T2   + 4608;
static const size_t OFF_CS    = OFF_TE   + 4608;          // [3][192]
// total ~6.8M floats ~27.2 MB

__device__ __forceinline__ float blo(u32 u) { return __uint_as_float(u << 16); }
__device__ __forceinline__ float bhi(u32 u) { return __uint_as_float(u & 0xFFFF0000u); }
__device__ __forceinline__ u16 pbf(float x) {
    u32 u = __float_as_uint(x);
    return (u16)((u + 0x7FFFu + ((u >> 16) & 1u)) >> 16);   // RNE; finite inputs
}
__device__ __forceinline__ u32 pack2(float lo, float hi) {
    return (u32)pbf(lo) | ((u32)pbf(hi) << 16);
}

// ---------------- K0: attr-independent edge features (bf16-packed) ----------------
__global__ __launch_bounds__(256) void k_edge(
    const float* __restrict__ E,
    const float* __restrict__ we0, const float* __restrict__ aen0,
    const float* __restrict__ we1, const float* __restrict__ aen1,
    uint2* __restrict__ fe0, u32* __restrict__ et0,
    u32* __restrict__ fe1, u32* __restrict__ et1)
{
    __shared__ float w0s[96], a0s[32], w1s[512], a1s[16];
    int tid = threadIdx.x;
    for (int i = tid; i < 96;  i += 256) w0s[i] = we0[i];
    for (int i = tid; i < 32;  i += 256) a0s[i] = aen0[i];
    for (int i = tid; i < 512; i += 256) w1s[i] = we1[i];
    for (int i = tid; i < 16;  i += 256) a1s[i] = aen1[i];
    __syncthreads();
    int e = blockIdx.x * 256 + tid;
    float E0 = E[e], E1 = E[NE_ + e], E2 = E[2 * NE_ + e];
    float f0[32];
    #pragma unroll
    for (int h = 0; h < 8; h++) {
        #pragma unroll
        for (int f = 0; f < 4; f++)
            f0[h*4+f] = E0*w0s[h*12+f] + E1*w0s[h*12+4+f] + E2*w0s[h*12+8+f];
        float tv = f0[h*4]*a0s[h*4] + f0[h*4+1]*a0s[h*4+1]
                 + f0[h*4+2]*a0s[h*4+2] + f0[h*4+3]*a0s[h*4+3];
        et0[h*NE_ + e] = pack2(__expf(tv), __expf(0.2f*tv));
        fe0[h*NE_ + e] = make_uint2(pack2(f0[h*4], f0[h*4+1]), pack2(f0[h*4+2], f0[h*4+3]));
    }
    #pragma unroll
    for (int h = 0; h < 8; h++) {
        float a = 0.f, b = 0.f;
        #pragma unroll
        for (int d = 0; d < 32; d++) {
            a += f0[d] * w1s[(h*32+d)*2];
            b += f0[d] * w1s[(h*32+d)*2+1];
        }
        fe1[h*NE_ + e] = pack2(a, b);
        float tv = a*a1s[h*2] + b*a1s[h*2+1];
        et1[h*NE_ + e] = pack2(__expf(tv), __expf(0.2f*tv));
    }
}

// ---------------- K0b: eadjP[e2][n] = bf16 pair (exp(adj[n][2e2]), exp(adj[n][2e2+1])) ----------------
// Transposed+pair-packed so k_att3 lanes (n-consecutive) load coalesced u32.
__global__ __launch_bounds__(192) void k_eadjP(
    const float* __restrict__ adj, u32* __restrict__ eadjP)
{
    int n = threadIdx.x;
    int e2base = blockIdx.x * 64;
    const float* ap = adj + (size_t)n * NE_ + 2 * e2base;
    #pragma unroll 4
    for (int i = 0; i < 64; i++) {
        float2 v = *(const float2*)(ap + 2*i);
        eadjP[(size_t)(e2base + i) * NN + n] = pack2(__expf(v.x), __expf(v.y));
    }
}

// ---------------- K0c: es/es5[a][h][n] = exp(s), exp(.2 s) ----------------
template<int DIN, int F>
__global__ __launch_bounds__(192) void k_s(
    const float* __restrict__ Xh, int xstride,
    const float* __restrict__ wn,   // [A][H][DIN][F]
    const float* __restrict__ aes,  // [H][F]
    float* __restrict__ es, float* __restrict__ es5)
{
    int ah = blockIdx.x;
    int a = ah / NH, h = ah % NH;
    int n = threadIdx.x;
    __shared__ float wt[DIN];
    if (n < DIN) {
        float w = 0.f;
        const float* wp = wn + (((size_t)a*NH + h)*DIN + n)*F;
        #pragma unroll
        for (int f = 0; f < F; f++) w += wp[f] * aes[h*F + f];
        wt[n] = w;
    }
    __syncthreads();
    const float* xp = Xh + (size_t)a*xstride + n*DIN;
    float s = 0.f;
    #pragma unroll
    for (int d = 0; d < DIN; d++) s += xp[d] * wt[d];
    es[ah*NN + n]  = __expf(s);
    es5[ah*NN + n] = __expf(0.2f*s);
}

// ---------------- K1: streaming e2n attention ----------------
// lane&15 -> n (16 n per block), lane>>4 -> e-subgroup (2 e each), wave -> head.
// w(n,e) = max(es*et, es5*et5)*eadj, accumulated per-lane for OWN n: no LDS,
// no barrier, 2-step shfl epilogue. Grid (S=64 e-splits, 12 n-tiles) = 768
// blocks = exactly 3/CU at __launch_bounds__(512,3).
template<int FE>
__global__ __launch_bounds__(512, 3) void k_att3(
    const float* __restrict__ es_,   // [A][H][N]
    const float* __restrict__ es5_,  // [A][H][N]
    const u32* __restrict__ etb,     // [H][NE] packed (et, et5)
    const u32* __restrict__ feb,     // [H][NE * FE/2] packed fe
    const u32* __restrict__ eadjP,   // [NE/2][N]
    float* __restrict__ part)        // [A][N][H][FE+1][S]
{
    constexpr int S = 64, EPB = NE_/S, STEPS = EPB/8;
    int h = threadIdx.x >> 6, lane = threadIdx.x & 63;
    int nidx = lane & 15, eg = lane >> 4;
    int split = blockIdx.x;
    int n = blockIdx.y * 16 + nidx;

    float es[NBA], es5[NBA];
    #pragma unroll
    for (int a = 0; a < NBA; a++) {
        es[a]  = es_[(a*NH + h)*NN + n];
        es5[a] = es5_[(a*NH + h)*NN + n];
    }

    float acc[NBA][FE+1];
    #pragma unroll
    for (int a = 0; a < NBA; a++)
        #pragma unroll
        for (int j = 0; j <= FE; j++) acc[a][j] = 0.f;

    int e0 = split * EPB;
    const u32* etp = etb + (size_t)h * NE_ + e0 + eg*2;
    const u32* fep = feb + ((size_t)h * NE_ + e0 + eg*2) * (FE/2);
    const u32* eap = eadjP + (size_t)(e0 >> 1) * NN + (size_t)eg * NN + n;

    #pragma unroll 4
    for (int st = 0; st < STEPS; st++) {
        uint2 etv = *(const uint2*)(etp + st*8);
        u32 eaU = eap[(size_t)st*4*NN];
        float fv0[FE], fv1[FE];
        if constexpr (FE == 4) {
            uint4 fq = *(const uint4*)(fep + st*16);
            fv0[0]=blo(fq.x); fv0[1]=bhi(fq.x); fv0[2]=blo(fq.y); fv0[3]=bhi(fq.y);
            fv1[0]=blo(fq.z); fv1[1]=bhi(fq.z); fv1[2]=blo(fq.w); fv1[3]=bhi(fq.w);
        } else {
            uint2 fq = *(const uint2*)(fep + st*8);
            fv0[0]=blo(fq.x); fv0[1]=bhi(fq.x);
            fv1[0]=blo(fq.y); fv1[1]=bhi(fq.y);
        }
        float ea0 = blo(eaU), ea1 = bhi(eaU);
        float g10 = blo(etv.x)*ea0, g20 = bhi(etv.x)*ea0;
        float g11 = blo(etv.y)*ea1, g21 = bhi(etv.y)*ea1;
        #pragma unroll
        for (int a = 0; a < NBA; a++) {
            float w0 = fmaxf(es[a]*g10, es5[a]*g20);
            float w1 = fmaxf(es[a]*g11, es5[a]*g21);
            acc[a][FE] += w0 + w1;
            #pragma unroll
            for (int f = 0; f < FE; f++) acc[a][f] += w0*fv0[f] + w1*fv1[f];
        }
    }

    // combine the 4 e-subgroups: lanes {nidx, +16, +32, +48}
    #pragma unroll
    for (int a = 0; a < NBA; a++)
        #pragma unroll
        for (int j = 0; j <= FE; j++) {
            float v = acc[a][j];
            v += __shfl_xor(v, 16);
            v += __shfl_xor(v, 32);
            acc[a][j] = v;
        }
    if (lane < 16) {
        #pragma unroll
        for (int a = 0; a < NBA; a++)
            #pragma unroll
            for (int j = 0; j <= FE; j++)
                part[((((size_t)a*NN + n)*NH + h)*(FE+1) + j)*S + split] = acc[a][j];
    }
}

// ---------------- K2: combine partials; f2, s2, t2 (grid.y = attr) ----------------
template<int DIN, int F, int FE>
__global__ __launch_bounds__(256) void k_mid(
    const float* __restrict__ Xh, int xstride,
    const float* __restrict__ wn,   // [A][H][DIN][F]
    const float* __restrict__ be,   // [H][FE]
    const float* __restrict__ wct,  // [H][F+FE][F]
    const float* __restrict__ bct,  // [H][F]
    const float* __restrict__ asf,  // [A][H][F]
    const float* __restrict__ anf,  // [A][H][F]
    const float* __restrict__ part, // [A][N][H][FE+1][S]
    float* __restrict__ f2, float* __restrict__ s2, float* __restrict__ t2)
{
    constexpr int S = 64, DCT = F + FE;
    int n = blockIdx.x, attr = blockIdx.y;
    int h = threadIdx.x >> 5, lane = threadIdx.x & 31;
    const float* Xp = Xh + (size_t)attr*xstride;
    const float* wnp = wn + (size_t)attr*NH*DIN*F;
    float* f2p = f2 + (size_t)attr*NH*NN*16;
    float v = 0.f;
    if (lane <= FE) {
        const float4* pp = (const float4*)(part +
            ((((size_t)attr*NN + n)*NH + h)*(FE+1) + lane)*S);
        #pragma unroll
        for (int s4 = 0; s4 < S/4; s4++) {
            float4 q = pp[s4];
            v += (q.x + q.y) + (q.z + q.w);
        }
    }
    float den = __shfl(v, FE, 32);
    float nfe = (lane < FE) ? v/den + be[h*FE+lane] : 0.f;
    float fv = 0.f;
    if (lane < F) {
        for (int d = 0; d < DIN; d++) fv += Xp[n*DIN+d] * wnp[(h*DIN+d)*F+lane];
    }
    __shared__ float c[NH][DCT];
    if (lane < F)  c[h][lane]     = fv;
    if (lane < FE) c[h][F + lane] = nfe;
    __syncthreads();
    float f2v = 0.f;
    if (lane < F) {
        f2v = bct[h*F+lane];
        #pragma unroll
        for (int d = 0; d < DCT; d++) f2v += c[h][d] * wct[(h*DCT+d)*F+lane];
        f2p[((size_t)h*NN + n)*16 + lane] = f2v;
    }
    float s2p = (lane < F) ? f2v * asf[attr*NH*F + h*F+lane] : 0.f;
    float t2p = (lane < F) ? f2v * anf[attr*NH*F + h*F+lane] : 0.f;
    #pragma unroll
    for (int m = 1; m < 32; m <<= 1) { s2p += __shfl_xor(s2p, m); t2p += __shfl_xor(t2p, m); }
    if (lane == 0) { s2[attr*NH*NN + h*NN+n] = s2p; t2[attr*NH*NN + h*NN+n] = t2p; }
}

// ---------------- K3: tE[h,k] = sum_m t2[h,m]*Einfo[m,k]; colsum (grid.y=attr) ----------------
__global__ __launch_bounds__(192) void k_te(
    const float* __restrict__ Einfo, size_t estride,
    const float* __restrict__ t2,
    float* __restrict__ tE, float* __restrict__ cs)
{
    int h = blockIdx.x, attr = blockIdx.y, k = threadIdx.x;
    const float* Ep = Einfo + (size_t)attr*estride;
    float a = 0.f, c = 0.f;
    for (int m = 0; m < NN; m++) {
        float ev = Ep[m*NN + k];
        a += t2[attr*NH*NN + h*NN + m] * ev;
        c += ev;
    }
    tE[attr*NH*NN + h*NN + k] = a;
    if (h == 0) cs[attr*NN + k] = c;
}

// ---------------- K4: att2 rows, nf, outputs (grid.y = attr) ----------------
template<int F, int LAYER>
__global__ __launch_bounds__(256) void k_out(
    const float* __restrict__ A,    // [A][N][N]
    const float* __restrict__ s2, const float* __restrict__ tE,
    const float* __restrict__ cs, const float* __restrict__ f2,
    const float* __restrict__ bn,   // [A][H][F]
    const float* __restrict__ X,
    float* __restrict__ out,
    float* __restrict__ xh1, float* __restrict__ einfo)
{
    int n = blockIdx.x, attr = blockIdx.y;
    int h = threadIdx.x >> 5, lane = threadIdx.x & 31;
    const float* Aattr = A + (size_t)attr*NE_;
    const float* f2p = f2 + (size_t)attr*NH*NN*16;
    float s2h = s2[attr*NH*NN + h*NN + n];
    float z[6];
    #pragma unroll
    for (int c6 = 0; c6 < 6; c6++) {
        int k = lane + 32*c6;
        float d2v = s2h * cs[attr*NN + k] + tE[attr*NH*NN + h*NN + k];
        z[c6] = fmaxf(d2v, 0.2f*d2v) + Aattr[n*NN + k];
    }
    float mx = z[0];
    #pragma unroll
    for (int c6 = 1; c6 < 6; c6++) mx = fmaxf(mx, z[c6]);
    #pragma unroll
    for (int m = 1; m < 32; m <<= 1) mx = fmaxf(mx, __shfl_xor(mx, m));
    float w[6], den = 0.f;
    #pragma unroll
    for (int c6 = 0; c6 < 6; c6++) { w[c6] = __expf(z[c6] - mx); den += w[c6]; }
    #pragma unroll
    for (int m = 1; m < 32; m <<= 1) den += __shfl_xor(den, m);
    __shared__ float attL[NH][NN];
    #pragma unroll
    for (int c6 = 0; c6 < 6; c6++) attL[h][lane + 32*c6] = w[c6];
    __syncthreads();
    if (lane < F) {
        float r = 0.f;
        for (int k = 0; k < NN; k++) r += attL[h][k] * f2p[((size_t)h*NN + k)*16 + lane];
        r = r/den + bn[attr*NH*F + h*F + lane];
        r = r > 0.f ? r : __expf(r) - 1.f;   // elu
        out[((size_t)n*NBA + attr)*OUTC + (LAYER == 0 ? 10 : 138) + h*F + lane] = r;
        if (LAYER == 0) xh1[(size_t)attr*NN*128 + n*128 + h*16 + lane] = r;
    }
    if (LAYER == 0 && h == 7) {
        #pragma unroll
        for (int c6 = 0; c6 < 6; c6++)
            einfo[(size_t)attr*NE_ + n*NN + lane + 32*c6] = w[c6] / den;
    }
    if (LAYER == 0 && h == 0 && lane < ND)
        out[((size_t)n*NBA + attr)*OUTC + lane] = X[n*ND + lane];
}

extern "C" void kernel_launch(void* const* d_in, const int* in_sizes, int n_in,
                              void* d_out, int out_size, void* d_ws, size_t ws_size,
                              hipStream_t stream) {
    const float* X    = (const float*)d_in[0];
    const float* A    = (const float*)d_in[1];
    const float* E    = (const float*)d_in[2];
    const float* adj  = (const float*)d_in[3];
    const float* w_n0 = (const float*)d_in[4];
    const float* b_n0 = (const float*)d_in[5];
    const float* as0  = (const float*)d_in[6];
    const float* an0  = (const float*)d_in[7];
    const float* w_n1 = (const float*)d_in[8];
    const float* b_n1 = (const float*)d_in[9];
    const float* as1  = (const float*)d_in[10];
    const float* an1  = (const float*)d_in[11];
    const float* w_e0 = (const float*)d_in[12];
    const float* b_e0 = (const float*)d_in[13];
    const float* w_ct0= (const float*)d_in[14];
    const float* b_ct0= (const float*)d_in[15];
    const float* aes0 = (const float*)d_in[16];
    const float* aen0 = (const float*)d_in[17];
    const float* w_e1 = (const float*)d_in[18];
    const float* b_e1 = (const float*)d_in[19];
    const float* w_ct1= (const float*)d_in[20];
    const float* b_ct1= (const float*)d_in[21];
    const float* aes1 = (const float*)d_in[22];
    const float* aen1 = (const float*)d_in[23];

    float* w      = (float*)d_ws;
    uint2* fe0b   = (uint2*)(w + OFF_FE0B);
    u32*   et0b   = (u32*)(w + OFF_ET0B);
    u32*   fe1b   = (u32*)(w + OFF_FE1B);
    u32*   et1b   = (u32*)(w + OFF_ET1B);
    u32*   eadjP  = (u32*)(w + OFF_EADJP);
    float* xh1    = w + OFF_XH1;
    float* einfo  = w + OFF_EINF;
    float* es     = w + OFF_ES;
    float* es5    = w + OFF_ES5;
    float* part   = w + OFF_PART;
    float* f2     = w + OFF_F2;
    float* s2     = w + OFF_S2;
    float* t2     = w + OFF_T2;
    float* tE     = w + OFF_TE;
    float* cs     = w + OFF_CS;
    float* out    = (float*)d_out;

    k_edge<<<dim3(NE_/256), dim3(256), 0, stream>>>(E, w_e0, aen0, w_e1, aen1,
                                                    fe0b, et0b, fe1b, et1b);
    k_eadjP<<<dim3((NE_/2)/64), dim3(192), 0, stream>>>(adj, eadjP);

    // ---- layer 0 ----
    k_s<10,16><<<dim3(24), dim3(192), 0, stream>>>(X, 0, w_n0, aes0, es, es5);
    k_att3<4><<<dim3(64,12), dim3(512), 0, stream>>>(
        es, es5, et0b, (const u32*)fe0b, eadjP, part);
    k_mid<10,16,4><<<dim3(NN,NBA), dim3(256), 0, stream>>>(
        X, 0, w_n0, b_e0, w_ct0, b_ct0, as0, an0, part, f2, s2, t2);
    k_te<<<dim3(8,NBA), dim3(192), 0, stream>>>(E, (size_t)NE_, t2, tE, cs);
    k_out<16,0><<<dim3(NN,NBA), dim3(256), 0, stream>>>(
        A, s2, tE, cs, f2, b_n0, X, out, xh1, einfo);

    // ---- layer 1 ----
    k_s<128,8><<<dim3(24), dim3(192), 0, stream>>>(xh1, NN*128, w_n1, aes1, es, es5);
    k_att3<2><<<dim3(64,12), dim3(512), 0, stream>>>(
        es, es5, et1b, fe1b, eadjP, part);
    k_mid<128,8,2><<<dim3(NN,NBA), dim3(256), 0, stream>>>(
        xh1, NN*128, w_n1, b_e1, w_ct1, b_ct1, as1, an1, part, f2, s2, t2);
    k_te<<<dim3(8,NBA), dim3(192), 0, stream>>>(einfo, (size_t)NE_, t2, tE, cs);
    k_out<8,1><<<dim3(NN,NBA), dim3(256), 0, stream>>>(
        A, s2, tE, cs, f2, b_n1, X, out, xh1, einfo);
}

// Round 7
// 156.736 us; speedup vs baseline: 3.5009x; 1.2207x over previous
//
#include <hip/hip_runtime.h>
#include <hip/hip_bf16.h>

#define NN 192
#define NBA 3
#define NH 8
#define ND 10
#define NE_ (NN*NN)          // 36864
#define OUTC 202             // 10 + 8*16 + 8*8

typedef unsigned int u32;
typedef unsigned short u16;
typedef __attribute__((ext_vector_type(8))) short bf16x8;
typedef __attribute__((ext_vector_type(4))) float f32x4;

// ---- workspace layout (float-sized slots) ----
static const size_t OFF_ET0B  = 0;                       // [8][NE] u32 (et,et5 bf16 pair)
static const size_t OFF_ET1B  = 294912;                  // [8][NE] u32
static const size_t OFF_FT0   = 589824;                  // [8][4][NE] u16 bf16 (feT, layer0)
static const size_t OFF_FT1   = 1179648;                 // [8][2][NE] u16 bf16
static const size_t OFF_EADJT = 1474560;                 // [192][NE] u16 bf16 exp(adj)
static const size_t OFF_XH1   = 5013504;                 // [3][192][128] f32
static const size_t OFF_EINF  = 5087232;                 // [3][192][192]
static const size_t OFF_ES    = 5197824;                 // [3][8][192]
static const size_t OFF_ES5   = 5202432;
static const size_t OFF_PART  = 5207040;                 // [3][48][12][8][FE+1][16] (L0: 1.1M f)
static const size_t OFF_F2    = 6312960;                 // [3][8][192][16]
static const size_t OFF_S2    = 6386688;
static const size_t OFF_T2    = 6391296;
static const size_t OFF_TE    = 6395904;
static const size_t OFF_CS    = 6400512;                 // [3][192]
// total ~6.40M floats ~25.6 MB

__device__ __forceinline__ float blo(u32 u) { return __uint_as_float(u << 16); }
__device__ __forceinline__ float bhi(u32 u) { return __uint_as_float(u & 0xFFFF0000u); }
__device__ __forceinline__ u16 pbf(float x) {
    u32 u = __float_as_uint(x);
    return (u16)((u + 0x7FFFu + ((u >> 16) & 1u)) >> 16);   // RNE; finite inputs
}
__device__ __forceinline__ u32 pack2(float lo, float hi) {
    return (u32)pbf(lo) | ((u32)pbf(hi) << 16);
}
__device__ __forceinline__ u32 cvtpk(float lo, float hi) {
    u32 r;
    asm("v_cvt_pk_bf16_f32 %0, %1, %2" : "=v"(r) : "v"(lo), "v"(hi));
    return r;
}

// ---------------- K0: attr-independent edge features (bf16, feT transposed) ----------------
__global__ __launch_bounds__(256) void k_edge(
    const float* __restrict__ E,
    const float* __restrict__ we0, const float* __restrict__ aen0,
    const float* __restrict__ we1, const float* __restrict__ aen1,
    u16* __restrict__ feT0, u32* __restrict__ et0,
    u16* __restrict__ feT1, u32* __restrict__ et1)
{
    __shared__ float w0s[96], a0s[32], w1s[512], a1s[16];
    int tid = threadIdx.x;
    for (int i = tid; i < 96;  i += 256) w0s[i] = we0[i];
    for (int i = tid; i < 32;  i += 256) a0s[i] = aen0[i];
    for (int i = tid; i < 512; i += 256) w1s[i] = we1[i];
    for (int i = tid; i < 16;  i += 256) a1s[i] = aen1[i];
    __syncthreads();
    int e = blockIdx.x * 256 + tid;
    float E0 = E[e], E1 = E[NE_ + e], E2 = E[2 * NE_ + e];
    float f0[32];
    #pragma unroll
    for (int h = 0; h < 8; h++) {
        #pragma unroll
        for (int f = 0; f < 4; f++) {
            f0[h*4+f] = E0*w0s[h*12+f] + E1*w0s[h*12+4+f] + E2*w0s[h*12+8+f];
            feT0[(size_t)(h*4+f)*NE_ + e] = pbf(f0[h*4+f]);
        }
        float tv = f0[h*4]*a0s[h*4] + f0[h*4+1]*a0s[h*4+1]
                 + f0[h*4+2]*a0s[h*4+2] + f0[h*4+3]*a0s[h*4+3];
        et0[h*NE_ + e] = pack2(__expf(tv), __expf(0.2f*tv));
    }
    #pragma unroll
    for (int h = 0; h < 8; h++) {
        float a = 0.f, b = 0.f;
        #pragma unroll
        for (int d = 0; d < 32; d++) {
            a += f0[d] * w1s[(h*32+d)*2];
            b += f0[d] * w1s[(h*32+d)*2+1];
        }
        feT1[(size_t)(h*2+0)*NE_ + e] = pbf(a);
        feT1[(size_t)(h*2+1)*NE_ + e] = pbf(b);
        float tv = a*a1s[h*2] + b*a1s[h*2+1];
        et1[h*NE_ + e] = pack2(__expf(tv), __expf(0.2f*tv));
    }
}

// ---------------- K0b: eadjT[n][e] = bf16(exp(adj[n][e])) ----------------
__global__ __launch_bounds__(256) void k_eadjT(
    const float* __restrict__ adj, u16* __restrict__ eadjT)
{
    int n = blockIdx.y;
    int e = (blockIdx.x * 256 + threadIdx.x) * 4;
    float4 v = *(const float4*)(adj + (size_t)n*NE_ + e);
    u32 p0 = pack2(__expf(v.x), __expf(v.y));
    u32 p1 = pack2(__expf(v.z), __expf(v.w));
    *(uint2*)(eadjT + (size_t)n*NE_ + e) = make_uint2(p0, p1);
}

// ---------------- K0c: es/es5[a][h][n] = exp(s), exp(.2 s) ----------------
template<int DIN, int F>
__global__ __launch_bounds__(192) void k_s(
    const float* __restrict__ Xh, int xstride,
    const float* __restrict__ wn,   // [A][H][DIN][F]
    const float* __restrict__ aes,  // [H][F]
    float* __restrict__ es, float* __restrict__ es5)
{
    int ah = blockIdx.x;
    int a = ah / NH, h = ah % NH;
    int n = threadIdx.x;
    __shared__ float wt[DIN];
    if (n < DIN) {
        float w = 0.f;
        const float* wp = wn + (((size_t)a*NH + h)*DIN + n)*F;
        #pragma unroll
        for (int f = 0; f < F; f++) w += wp[f] * aes[h*F + f];
        wt[n] = w;
    }
    __syncthreads();
    const float* xp = Xh + (size_t)a*xstride + n*DIN;
    float s = 0.f;
    #pragma unroll
    for (int d = 0; d < DIN; d++) s += xp[d] * wt[d];
    es[ah*NN + n]  = __expf(s);
    es5[ah*NN + n] = __expf(0.2f*s);
}

// ---------------- K1: e2n attention, MFMA accumulate ----------------
// wave = head. Per 32-e tile: lanes compute w[n=lane&15][e=kg*8+j] on VALU,
// cvt_pk to bf16 A-frag; B-frag = feT[f=lane&15][e] (col FE = 1.0 -> denominator).
// One mfma_f32_16x16x32_bf16 per attr. C: col=lane&15=f, row=(lane>>4)*4+j=n.
// Grid (S=48 e-splits, 12 n-tiles).
template<int FE>
__global__ __launch_bounds__(512, 3) void k_att3(
    const float* __restrict__ es_,   // [A][H][N]
    const float* __restrict__ es5_,  // [A][H][N]
    const u32* __restrict__ etb,     // [H][NE] (et, et5) bf16 pair
    const u16* __restrict__ feT,     // [H][FE][NE] bf16
    const u16* __restrict__ eadjT,   // [N][NE] bf16
    float* __restrict__ part)        // [A][S][12][H][FE+1][16]
{
    constexpr int S = 48, EPB = NE_/S, TILES = EPB/32;
    constexpr size_t PA = (size_t)S*12*NH*(FE+1)*16;   // per-attr stride
    int h = threadIdx.x >> 6, lane = threadIdx.x & 63;
    int fr = lane & 15, kg = lane >> 4;
    int split = blockIdx.x, ntile = blockIdx.y;
    int e0 = split * EPB;
    int nm = ntile*16 + fr;

    float esv[NBA], es5v[NBA];
    #pragma unroll
    for (int a = 0; a < NBA; a++) {
        esv[a]  = es_[(a*NH + h)*NN + nm];
        es5v[a] = es5_[(a*NH + h)*NN + nm];
    }

    int fclamp = fr < FE ? fr : FE-1;
    const u32* etp = etb + (size_t)h*NE_ + e0 + kg*8;
    const u16* eap = eadjT + (size_t)nm*NE_ + e0 + kg*8;
    const u16* fp  = feT + (size_t)(h*FE + fclamp)*NE_ + e0 + kg*8;
    u32 bkeep = fr < FE ? 0xFFFFFFFFu : 0u;
    u32 bfill = fr == FE ? 0x3F803F80u : 0u;   // bf16 1.0 pair

    f32x4 acc[NBA];
    #pragma unroll
    for (int a = 0; a < NBA; a++) acc[a] = (f32x4){0.f, 0.f, 0.f, 0.f};

    #pragma unroll 2
    for (int t = 0; t < TILES; t++) {
        int off = t*32;
        uint4 etq0 = *(const uint4*)(etp + off);
        uint4 etq1 = *(const uint4*)(etp + off + 4);
        uint4 eaq  = *(const uint4*)(eap + off);
        uint4 bq   = *(const uint4*)(fp  + off);
        bq.x = (bq.x & bkeep) | bfill;
        bq.y = (bq.y & bkeep) | bfill;
        bq.z = (bq.z & bkeep) | bfill;
        bq.w = (bq.w & bkeep) | bfill;
        union { uint4 u; bf16x8 s; } B; B.u = bq;

        u32 etw[8] = {etq0.x, etq0.y, etq0.z, etq0.w, etq1.x, etq1.y, etq1.z, etq1.w};
        u32 eaw[4] = {eaq.x, eaq.y, eaq.z, eaq.w};
        float g1[8], g2[8];
        #pragma unroll
        for (int j = 0; j < 8; j++) {
            float ea = (j & 1) ? bhi(eaw[j>>1]) : blo(eaw[j>>1]);
            g1[j] = blo(etw[j]) * ea;
            g2[j] = bhi(etw[j]) * ea;
        }
        #pragma unroll
        for (int a = 0; a < NBA; a++) {
            float w[8];
            #pragma unroll
            for (int j = 0; j < 8; j++)
                w[j] = fmaxf(esv[a]*g1[j], es5v[a]*g2[j]);
            union { uint4 u; bf16x8 s; } A;
            A.u.x = cvtpk(w[0], w[1]);
            A.u.y = cvtpk(w[2], w[3]);
            A.u.z = cvtpk(w[4], w[5]);
            A.u.w = cvtpk(w[6], w[7]);
            acc[a] = __builtin_amdgcn_mfma_f32_16x16x32_bf16(A.s, B.s, acc[a], 0, 0, 0);
        }
    }

    if (fr <= FE) {
        float* pp = part + ((((size_t)split*12 + ntile)*NH + h)*(FE+1) + fr)*16 + kg*4;
        #pragma unroll
        for (int a = 0; a < NBA; a++)
            *(f32x4*)(pp + (size_t)a*PA) = acc[a];
    }
}

// ---------------- K2: combine partials; f2, s2, t2 (grid.y = attr) ----------------
template<int DIN, int F, int FE>
__global__ __launch_bounds__(256) void k_mid(
    const float* __restrict__ Xh, int xstride,
    const float* __restrict__ wn,   // [A][H][DIN][F]
    const float* __restrict__ be,   // [H][FE]
    const float* __restrict__ wct,  // [H][F+FE][F]
    const float* __restrict__ bct,  // [H][F]
    const float* __restrict__ asf,  // [A][H][F]
    const float* __restrict__ anf,  // [A][H][F]
    const float* __restrict__ part, // [A][S][12][H][FE+1][16]
    float* __restrict__ f2, float* __restrict__ s2, float* __restrict__ t2)
{
    constexpr int S = 48, DCT = F + FE;
    constexpr size_t PA = (size_t)S*12*NH*(FE+1)*16;
    constexpr size_t SSTR = (size_t)12*NH*(FE+1)*16;
    int n = blockIdx.x, attr = blockIdx.y;
    int h = threadIdx.x >> 5, lane = threadIdx.x & 31;
    const float* Xp = Xh + (size_t)attr*xstride;
    const float* wnp = wn + (size_t)attr*NH*DIN*F;
    float* f2p = f2 + (size_t)attr*NH*NN*16;
    float v = 0.f;
    if (lane <= FE) {
        const float* pp = part + (size_t)attr*PA
            + (((size_t)(n >> 4)*NH + h)*(FE+1) + lane)*16 + (n & 15);
        #pragma unroll 4
        for (int s = 0; s < S; s++) v += pp[s*SSTR];
    }
    float den = __shfl(v, FE, 32);
    float nfe = (lane < FE) ? v/den + be[h*FE+lane] : 0.f;
    float fv = 0.f;
    if (lane < F) {
        for (int d = 0; d < DIN; d++) fv += Xp[n*DIN+d] * wnp[(h*DIN+d)*F+lane];
    }
    __shared__ float c[NH][DCT];
    if (lane < F)  c[h][lane]     = fv;
    if (lane < FE) c[h][F + lane] = nfe;
    __syncthreads();
    float f2v = 0.f;
    if (lane < F) {
        f2v = bct[h*F+lane];
        #pragma unroll
        for (int d = 0; d < DCT; d++) f2v += c[h][d] * wct[(h*DCT+d)*F+lane];
        f2p[((size_t)h*NN + n)*16 + lane] = f2v;
    }
    float s2p = (lane < F) ? f2v * asf[attr*NH*F + h*F+lane] : 0.f;
    float t2p = (lane < F) ? f2v * anf[attr*NH*F + h*F+lane] : 0.f;
    #pragma unroll
    for (int m = 1; m < 32; m <<= 1) { s2p += __shfl_xor(s2p, m); t2p += __shfl_xor(t2p, m); }
    if (lane == 0) { s2[attr*NH*NN + h*NN+n] = s2p; t2[attr*NH*NN + h*NN+n] = t2p; }
}

// ---------------- K3: tE[h,k] = sum_m t2[h,m]*Einfo[m,k]; colsum (grid.y=attr) ----------------
__global__ __launch_bounds__(192) void k_te(
    const float* __restrict__ Einfo, size_t estride,
    const float* __restrict__ t2,
    float* __restrict__ tE, float* __restrict__ cs)
{
    int h = blockIdx.x, attr = blockIdx.y, k = threadIdx.x;
    const float* Ep = Einfo + (size_t)attr*estride;
    float a = 0.f, c = 0.f;
    for (int m = 0; m < NN; m++) {
        float ev = Ep[m*NN + k];
        a += t2[attr*NH*NN + h*NN + m] * ev;
        c += ev;
    }
    tE[attr*NH*NN + h*NN + k] = a;
    if (h == 0) cs[attr*NN + k] = c;
}

// ---------------- K4: att2 rows, nf, outputs (grid.y = attr) ----------------
template<int F, int LAYER>
__global__ __launch_bounds__(256) void k_out(
    const float* __restrict__ A,    // [A][N][N]
    const float* __restrict__ s2, const float* __restrict__ tE,
    const float* __restrict__ cs, const float* __restrict__ f2,
    const float* __restrict__ bn,   // [A][H][F]
    const float* __restrict__ X,
    float* __restrict__ out,
    float* __restrict__ xh1, float* __restrict__ einfo)
{
    int n = blockIdx.x, attr = blockIdx.y;
    int h = threadIdx.x >> 5, lane = threadIdx.x & 31;
    const float* Aattr = A + (size_t)attr*NE_;
    const float* f2p = f2 + (size_t)attr*NH*NN*16;
    float s2h = s2[attr*NH*NN + h*NN + n];
    float z[6];
    #pragma unroll
    for (int c6 = 0; c6 < 6; c6++) {
        int k = lane + 32*c6;
        float d2v = s2h * cs[attr*NN + k] + tE[attr*NH*NN + h*NN + k];
        z[c6] = fmaxf(d2v, 0.2f*d2v) + Aattr[n*NN + k];
    }
    float mx = z[0];
    #pragma unroll
    for (int c6 = 1; c6 < 6; c6++) mx = fmaxf(mx, z[c6]);
    #pragma unroll
    for (int m = 1; m < 32; m <<= 1) mx = fmaxf(mx, __shfl_xor(mx, m));
    float w[6], den = 0.f;
    #pragma unroll
    for (int c6 = 0; c6 < 6; c6++) { w[c6] = __expf(z[c6] - mx); den += w[c6]; }
    #pragma unroll
    for (int m = 1; m < 32; m <<= 1) den += __shfl_xor(den, m);
    __shared__ float attL[NH][NN];
    #pragma unroll
    for (int c6 = 0; c6 < 6; c6++) attL[h][lane + 32*c6] = w[c6];
    __syncthreads();
    if (lane < F) {
        float r = 0.f;
        for (int k = 0; k < NN; k++) r += attL[h][k] * f2p[((size_t)h*NN + k)*16 + lane];
        r = r/den + bn[attr*NH*F + h*F + lane];
        r = r > 0.f ? r : __expf(r) - 1.f;   // elu
        out[((size_t)n*NBA + attr)*OUTC + (LAYER == 0 ? 10 : 138) + h*F + lane] = r;
        if (LAYER == 0) xh1[(size_t)attr*NN*128 + n*128 + h*16 + lane] = r;
    }
    if (LAYER == 0 && h == 7) {
        #pragma unroll
        for (int c6 = 0; c6 < 6; c6++)
            einfo[(size_t)attr*NE_ + n*NN + lane + 32*c6] = w[c6] / den;
    }
    if (LAYER == 0 && h == 0 && lane < ND)
        out[((size_t)n*NBA + attr)*OUTC + lane] = X[n*ND + lane];
}

extern "C" void kernel_launch(void* const* d_in, const int* in_sizes, int n_in,
                              void* d_out, int out_size, void* d_ws, size_t ws_size,
                              hipStream_t stream) {
    const float* X    = (const float*)d_in[0];
    const float* A    = (const float*)d_in[1];
    const float* E    = (const float*)d_in[2];
    const float* adj  = (const float*)d_in[3];
    const float* w_n0 = (const float*)d_in[4];
    const float* b_n0 = (const float*)d_in[5];
    const float* as0  = (const float*)d_in[6];
    const float* an0  = (const float*)d_in[7];
    const float* w_n1 = (const float*)d_in[8];
    const float* b_n1 = (const float*)d_in[9];
    const float* as1  = (const float*)d_in[10];
    const float* an1  = (const float*)d_in[11];
    const float* w_e0 = (const float*)d_in[12];
    const float* b_e0 = (const float*)d_in[13];
    const float* w_ct0= (const float*)d_in[14];
    const float* b_ct0= (const float*)d_in[15];
    const float* aes0 = (const float*)d_in[16];
    const float* aen0 = (const float*)d_in[17];
    const float* w_e1 = (const float*)d_in[18];
    const float* b_e1 = (const float*)d_in[19];
    const float* w_ct1= (const float*)d_in[20];
    const float* b_ct1= (const float*)d_in[21];
    const float* aes1 = (const float*)d_in[22];
    const float* aen1 = (const float*)d_in[23];

    float* w      = (float*)d_ws;
    u32*   et0b   = (u32*)(w + OFF_ET0B);
    u32*   et1b   = (u32*)(w + OFF_ET1B);
    u16*   feT0   = (u16*)(w + OFF_FT0);
    u16*   feT1   = (u16*)(w + OFF_FT1);
    u16*   eadjT  = (u16*)(w + OFF_EADJT);
    float* xh1    = w + OFF_XH1;
    float* einfo  = w + OFF_EINF;
    float* es     = w + OFF_ES;
    float* es5    = w + OFF_ES5;
    float* part   = w + OFF_PART;
    float* f2     = w + OFF_F2;
    float* s2     = w + OFF_S2;
    float* t2     = w + OFF_T2;
    float* tE     = w + OFF_TE;
    float* cs     = w + OFF_CS;
    float* out    = (float*)d_out;

    k_edge<<<dim3(NE_/256), dim3(256), 0, stream>>>(E, w_e0, aen0, w_e1, aen1,
                                                    feT0, et0b, feT1, et1b);
    k_eadjT<<<dim3(NE_/1024, NN), dim3(256), 0, stream>>>(adj, eadjT);

    // ---- layer 0 ----
    k_s<10,16><<<dim3(24), dim3(192), 0, stream>>>(X, 0, w_n0, aes0, es, es5);
    k_att3<4><<<dim3(48,12), dim3(512), 0, stream>>>(
        es, es5, et0b, feT0, eadjT, part);
    k_mid<10,16,4><<<dim3(NN,NBA), dim3(256), 0, stream>>>(
        X, 0, w_n0, b_e0, w_ct0, b_ct0, as0, an0, part, f2, s2, t2);
    k_te<<<dim3(8,NBA), dim3(192), 0, stream>>>(E, (size_t)NE_, t2, tE, cs);
    k_out<16,0><<<dim3(NN,NBA), dim3(256), 0, stream>>>(
        A, s2, tE, cs, f2, b_n0, X, out, xh1, einfo);

    // ---- layer 1 ----
    k_s<128,8><<<dim3(24), dim3(192), 0, stream>>>(xh1, NN*128, w_n1, aes1, es, es5);
    k_att3<2><<<dim3(48,12), dim3(512), 0, stream>>>(
        es, es5, et1b, feT1, eadjT, part);
    k_mid<128,8,2><<<dim3(NN,NBA), dim3(256), 0, stream>>>(
        xh1, NN*128, w_n1, b_e1, w_ct1, b_ct1, as1, an1, part, f2, s2, t2);
    k_te<<<dim3(8,NBA), dim3(192), 0, stream>>>(einfo, (size_t)NE_, t2, tE, cs);
    k_out<8,1><<<dim3(NN,NBA), dim3(256), 0, stream>>>(
        A, s2, tE, cs, f2, b_n1, X, out, xh1, einfo);
}

// Round 9
// 129.042 us; speedup vs baseline: 4.2523x; 1.2146x over previous
//
#include <hip/hip_runtime.h>
#include <hip/hip_bf16.h>

#define NN 192
#define NBA 3
#define NH 8
#define ND 10
#define NE_ (NN*NN)          // 36864
#define NE2 (NE_/2)          // 18432
#define OUTC 202             // 10 + 8*16 + 8*8

typedef unsigned int u32;
typedef unsigned short u16;
typedef __attribute__((ext_vector_type(2))) _Float16 h2v;
typedef __attribute__((ext_vector_type(8))) _Float16 f16x8;
typedef __attribute__((ext_vector_type(4))) float f32x4;

// ---- workspace layout (float-sized slots) ----
static const size_t OFF_ET0P  = 0;                        // [8][NE2] u32 half2 (et pairs)
static const size_t OFF_ET50P = OFF_ET0P  + 147456;
static const size_t OFF_ET1P  = OFF_ET50P + 147456;
static const size_t OFF_ET51P = OFF_ET1P  + 147456;
static const size_t OFF_FT0P  = OFF_ET51P + 147456;       // [8][4][NE2] u32 half2
static const size_t OFF_FT1P  = OFF_FT0P  + 589824;       // [8][2][NE2]
static const size_t OFF_EAP   = OFF_FT1P  + 294912;       // [192][NE2] u32 half2 exp(adj)
static const size_t OFF_XH1   = OFF_EAP   + 3538944;      // [3][192][128] f32
static const size_t OFF_EINF  = OFF_XH1   + 73728;        // [3][192][192]
static const size_t OFF_ES0   = OFF_EINF  + 110592;       // [3][8][192] u32 half2(es,es)
static const size_t OFF_ES50  = OFF_ES0   + 4608;
static const size_t OFF_ES1   = OFF_ES50  + 4608;
static const size_t OFF_ES51  = OFF_ES1   + 4608;
static const size_t OFF_WT1   = OFF_ES51  + 4608;         // [3][8][128] f32
static const size_t OFF_PART  = OFF_WT1   + 3072;         // [3][64][12][8][FE+1][16]
static const size_t OFF_F2    = OFF_PART  + 1474560;      // [3][8][192][16]
static const size_t OFF_S2    = OFF_F2    + 73728;
static const size_t OFF_T2    = OFF_S2    + 4608;
static const size_t OFF_TE    = OFF_T2    + 4608;
static const size_t OFF_CS    = OFF_TE    + 4608;         // [3][192]
// total ~6.78M floats ~27.1 MB

__device__ __forceinline__ u32 h2u(h2v h) { union { h2v h; u32 u; } c; c.h = h; return c.u; }
__device__ __forceinline__ h2v u2h(u32 u) { union { u32 u; h2v h; } c; c.u = u; return c.h; }
__device__ __forceinline__ u32 packh(float a, float b) {
    h2v h; h.x = (_Float16)a; h.y = (_Float16)b; return h2u(h);
}

// ---------------- K_PRE: all attr-independent preprocessing, one launch ----------------
// blocks [0,72):    edge features -> et0P/et50P/et1P/et51P/ft0P/ft1P (fp16 pairs)
// blocks [72,1800): eaP = fp16 pairs of exp(adj), [n][e/2]
// block  1800:      wt1[a][h][d] = sum_f wn1*aes1
// blocks [1801,1825): es0/es50 (layer-0 node logits)
__global__ __launch_bounds__(256) void k_pre(
    const float* __restrict__ E, const float* __restrict__ adj,
    const float* __restrict__ X,
    const float* __restrict__ we0, const float* __restrict__ aen0,
    const float* __restrict__ we1, const float* __restrict__ aen1,
    const float* __restrict__ wn0, const float* __restrict__ aes0,
    const float* __restrict__ wn1, const float* __restrict__ aes1,
    u32* __restrict__ et0P, u32* __restrict__ et50P,
    u32* __restrict__ et1P, u32* __restrict__ et51P,
    u32* __restrict__ ft0P, u32* __restrict__ ft1P,
    u32* __restrict__ eaP,
    u32* __restrict__ es0, u32* __restrict__ es50,
    float* __restrict__ wt1)
{
    int b = blockIdx.x, tid = threadIdx.x;
    if (b < 72) {
        __shared__ float w0s[96], a0s[32], w1s[512], a1s[16];
        for (int i = tid; i < 96;  i += 256) w0s[i] = we0[i];
        for (int i = tid; i < 32;  i += 256) a0s[i] = aen0[i];
        for (int i = tid; i < 512; i += 256) w1s[i] = we1[i];
        for (int i = tid; i < 16;  i += 256) a1s[i] = aen1[i];
        __syncthreads();
        int ep = b*256 + tid;            // e-pair index
        int e0 = 2*ep;
        float2 E0 = *(const float2*)(E + e0);
        float2 E1 = *(const float2*)(E + NE_ + e0);
        float2 E2 = *(const float2*)(E + 2*NE_ + e0);
        float fa[32], fb[32];
        #pragma unroll
        for (int h = 0; h < 8; h++) {
            float ta = 0.f, tb = 0.f;
            #pragma unroll
            for (int f = 0; f < 4; f++) {
                float wa = w0s[h*12+f], wb = w0s[h*12+4+f], wc = w0s[h*12+8+f];
                float va = E0.x*wa + E1.x*wb + E2.x*wc;
                float vb = E0.y*wa + E1.y*wb + E2.y*wc;
                fa[h*4+f] = va; fb[h*4+f] = vb;
                ft0P[(size_t)(h*4+f)*NE2 + ep] = packh(va, vb);
                ta += va * a0s[h*4+f];
                tb += vb * a0s[h*4+f];
            }
            et0P [h*NE2 + ep] = packh(__expf(ta), __expf(tb));
            et50P[h*NE2 + ep] = packh(__expf(0.2f*ta), __expf(0.2f*tb));
        }
        #pragma unroll
        for (int h = 0; h < 8; h++) {
            float aa = 0.f, ba = 0.f, ab = 0.f, bb = 0.f;
            #pragma unroll
            for (int d = 0; d < 32; d++) {
                float w0 = w1s[(h*32+d)*2], w1 = w1s[(h*32+d)*2+1];
                aa += fa[d] * w0;  ba += fa[d] * w1;
                ab += fb[d] * w0;  bb += fb[d] * w1;
            }
            ft1P[(size_t)(h*2+0)*NE2 + ep] = packh(aa, ab);
            ft1P[(size_t)(h*2+1)*NE2 + ep] = packh(ba, bb);
            float ta = aa*a1s[h*2] + ba*a1s[h*2+1];
            float tb = ab*a1s[h*2] + bb*a1s[h*2+1];
            et1P [h*NE2 + ep] = packh(__expf(ta), __expf(tb));
            et51P[h*NE2 + ep] = packh(__expf(0.2f*ta), __expf(0.2f*tb));
        }
    } else if (b < 1800) {
        int idx = (b - 72)*256 + tid;      // [0, 442368)
        int n = idx / 2304, c8 = idx % 2304;
        const float* ap = adj + (size_t)n*NE_ + c8*16;
        u32 o[8];
        #pragma unroll
        for (int q = 0; q < 4; q++) {
            float4 v = *(const float4*)(ap + q*4);
            o[2*q]   = packh(__expf(v.x), __expf(v.y));
            o[2*q+1] = packh(__expf(v.z), __expf(v.w));
        }
        u32* dst = eaP + (size_t)n*NE2 + c8*8;
        *(uint4*)(dst)     = make_uint4(o[0], o[1], o[2], o[3]);
        *(uint4*)(dst + 4) = make_uint4(o[4], o[5], o[6], o[7]);
    } else if (b == 1800) {
        for (int v = tid; v < 3072; v += 256) {
            int a = v >> 10, rem = v & 1023, h = rem >> 7, d = rem & 127;
            float w = 0.f;
            #pragma unroll
            for (int f = 0; f < 8; f++)
                w += wn1[(((size_t)a*NH + h)*128 + d)*8 + f] * aes1[h*8 + f];
            wt1[v] = w;
        }
    } else {
        int ah = b - 1801;
        int a = ah / NH, h = ah % NH;
        __shared__ float wt0[ND];
        if (tid < ND) {
            float w = 0.f;
            #pragma unroll
            for (int f = 0; f < 16; f++)
                w += wn0[(((size_t)a*NH + h)*ND + tid)*16 + f] * aes0[h*16 + f];
            wt0[tid] = w;
        }
        __syncthreads();
        if (tid < NN) {
            float s = 0.f;
            #pragma unroll
            for (int d = 0; d < ND; d++) s += X[tid*ND + d] * wt0[d];
            es0 [ah*NN + tid] = packh(__expf(s), __expf(s));
            es50[ah*NN + tid] = packh(__expf(0.2f*s), __expf(0.2f*s));
        }
    }
}

// ---------------- K1: e2n attention, fp16 pk-math + f16 MFMA ----------------
// wave = head; lane (fr=lane&15, kg=lane>>4). A-row = n = ntile*16+fr; k = e.
// w = pk_max(es*et*ea, es5*et5*ea) — all fp16 pairs (values <= ~e^7, fp16-safe).
// B rows fr<FE from ft*P, fr==FE constant 1.0 (denominator), fr>FE zero (no load).
// Grid (S=64 e-splits, 12 n-tiles) = 768 blocks = 3/CU.
template<int FE>
__global__ __launch_bounds__(512, 3) void k_att3(
    const u32* __restrict__ es_,   // [A][H][N] half2(es,es)
    const u32* __restrict__ es5_,  // [A][H][N]
    const u32* __restrict__ etP,   // [H][NE2]
    const u32* __restrict__ et5P,  // [H][NE2]
    const u32* __restrict__ feP,   // [H][FE][NE2]
    const u32* __restrict__ eaP,   // [N][NE2]
    float* __restrict__ part)      // [A][S][12][H][FE+1][16]
{
    constexpr int S = 64, EPB = NE_/S, TILES = EPB/32;   // EPB=576, TILES=18
    constexpr size_t PA = (size_t)S*12*NH*(FE+1)*16;
    int h = threadIdx.x >> 6, lane = threadIdx.x & 63;
    int fr = lane & 15, kg = lane >> 4;
    int split = blockIdx.x, ntile = blockIdx.y;
    int nm = ntile*16 + fr;
    int p0 = split*(EPB/2) + kg*4;     // u32 (pair) offset within row

    h2v esh[NBA], es5h[NBA];
    #pragma unroll
    for (int a = 0; a < NBA; a++) {
        esh[a]  = u2h(es_ [(a*NH + h)*NN + nm]);
        es5h[a] = u2h(es5_[(a*NH + h)*NN + nm]);
    }

    const u32* etp  = etP  + (size_t)h*NE2 + p0;
    const u32* et5p = et5P + (size_t)h*NE2 + p0;
    const u32* eap  = eaP  + (size_t)nm*NE2 + p0;
    const u32* fp   = feP  + ((size_t)h*FE + (fr < FE ? fr : 0))*NE2 + p0;
    u32 bfill = (fr == FE) ? 0x3C003C00u : 0u;   // fp16 1.0 pair / 0
    uint4 bc = make_uint4(bfill, bfill, bfill, bfill);

    f32x4 acc[NBA];
    #pragma unroll
    for (int a = 0; a < NBA; a++) acc[a] = (f32x4){0.f, 0.f, 0.f, 0.f};

    #pragma unroll 2
    for (int t = 0; t < TILES; t++) {
        uint4 etq  = *(const uint4*)(etp  + t*16);
        uint4 et5q = *(const uint4*)(et5p + t*16);
        uint4 eaq  = *(const uint4*)(eap  + t*16);
        uint4 bq = bc;
        if (fr < FE) bq = *(const uint4*)(fp + t*16);
        union { uint4 u; f16x8 v; } B; B.u = bq;

        u32 etw[4]  = {etq.x,  etq.y,  etq.z,  etq.w};
        u32 et5w[4] = {et5q.x, et5q.y, et5q.z, et5q.w};
        u32 eaw[4]  = {eaq.x,  eaq.y,  eaq.z,  eaq.w};
        h2v g1[4], g2[4];
        #pragma unroll
        for (int p = 0; p < 4; p++) {
            h2v ea = u2h(eaw[p]);
            g1[p] = u2h(etw[p])  * ea;
            g2[p] = u2h(et5w[p]) * ea;
        }
        #pragma unroll
        for (int a = 0; a < NBA; a++) {
            union { uint4 u; f16x8 v; } A;
            u32 aw[4];
            #pragma unroll
            for (int p = 0; p < 4; p++) {
                h2v wv = __builtin_elementwise_max(esh[a] * g1[p], es5h[a] * g2[p]);
                aw[p] = h2u(wv);
            }
            A.u = make_uint4(aw[0], aw[1], aw[2], aw[3]);
            acc[a] = __builtin_amdgcn_mfma_f32_16x16x32_f16(A.v, B.v, acc[a], 0, 0, 0);
        }
    }

    if (fr <= FE) {
        float* pp = part + ((((size_t)split*12 + ntile)*NH + h)*(FE+1) + fr)*16 + kg*4;
        #pragma unroll
        for (int a = 0; a < NBA; a++)
            *(f32x4*)(pp + (size_t)a*PA) = acc[a];
    }
}

// ---------------- K2: combine partials; f2, s2, t2 (grid.y = attr) ----------------
template<int DIN, int F, int FE>
__global__ __launch_bounds__(256) void k_mid(
    const float* __restrict__ Xh, int xstride,
    const float* __restrict__ wn,   // [A][H][DIN][F]
    const float* __restrict__ be,   // [H][FE]
    const float* __restrict__ wct,  // [H][F+FE][F]
    const float* __restrict__ bct,  // [H][F]
    const float* __restrict__ asf,  // [A][H][F]
    const float* __restrict__ anf,  // [A][H][F]
    const float* __restrict__ part, // [A][S][12][H][FE+1][16]
    float* __restrict__ f2, float* __restrict__ s2, float* __restrict__ t2)
{
    constexpr int S = 64, DCT = F + FE;
    constexpr size_t PA = (size_t)S*12*NH*(FE+1)*16;
    constexpr size_t SSTR = (size_t)12*NH*(FE+1)*16;
    int n = blockIdx.x, attr = blockIdx.y;
    int h = threadIdx.x >> 5, lane = threadIdx.x & 31;
    const float* Xp = Xh + (size_t)attr*xstride;
    const float* wnp = wn + (size_t)attr*NH*DIN*F;
    float* f2p = f2 + (size_t)attr*NH*NN*16;
    float v = 0.f;
    if (lane <= FE) {
        const float* pp = part + (size_t)attr*PA
            + (((size_t)(n >> 4)*NH + h)*(FE+1) + lane)*16 + (n & 15);
        #pragma unroll 8
        for (int s = 0; s < S; s++) v += pp[s*SSTR];
    }
    float den = __shfl(v, FE, 32);
    float nfe = (lane < FE) ? v/den + be[h*FE+lane] : 0.f;
    float fv = 0.f;
    if (lane < F) {
        for (int d = 0; d < DIN; d++) fv += Xp[n*DIN+d] * wnp[(h*DIN+d)*F+lane];
    }
    __shared__ float c[NH][DCT];
    if (lane < F)  c[h][lane]     = fv;
    if (lane < FE) c[h][F + lane] = nfe;
    __syncthreads();
    float f2v = 0.f;
    if (lane < F) {
        f2v = bct[h*F+lane];
        #pragma unroll
        for (int d = 0; d < DCT; d++) f2v += c[h][d] * wct[(h*DCT+d)*F+lane];
        f2p[((size_t)h*NN + n)*16 + lane] = f2v;
    }
    float s2p = (lane < F) ? f2v * asf[attr*NH*F + h*F+lane] : 0.f;
    float t2p = (lane < F) ? f2v * anf[attr*NH*F + h*F+lane] : 0.f;
    #pragma unroll
    for (int m = 1; m < 32; m <<= 1) { s2p += __shfl_xor(s2p, m); t2p += __shfl_xor(t2p, m); }
    if (lane == 0) { s2[attr*NH*NN + h*NN+n] = s2p; t2[attr*NH*NN + h*NN+n] = t2p; }
}

// ---------------- K3: tE[h,k] = sum_m t2[h,m]*Einfo[m,k]; colsum (grid.y=attr) ----------------
__global__ __launch_bounds__(192) void k_te(
    const float* __restrict__ Einfo, size_t estride,
    const float* __restrict__ t2,
    float* __restrict__ tE, float* __restrict__ cs)
{
    int h = blockIdx.x, attr = blockIdx.y, k = threadIdx.x;
    const float* Ep = Einfo + (size_t)attr*estride;
    float a = 0.f, c = 0.f;
    for (int m = 0; m < NN; m++) {
        float ev = Ep[m*NN + k];
        a += t2[attr*NH*NN + h*NN + m] * ev;
        c += ev;
    }
    tE[attr*NH*NN + h*NN + k] = a;
    if (h == 0) cs[attr*NN + k] = c;
}

// ---------------- K4: att2 rows, nf, outputs (grid.y = attr); L0 also emits es1 ----------------
template<int F, int LAYER>
__global__ __launch_bounds__(256) void k_out(
    const float* __restrict__ A,    // [A][N][N]
    const float* __restrict__ s2, const float* __restrict__ tE,
    const float* __restrict__ cs, const float* __restrict__ f2,
    const float* __restrict__ bn,   // [A][H][F]
    const float* __restrict__ X,
    float* __restrict__ out,
    float* __restrict__ xh1, float* __restrict__ einfo,
    const float* __restrict__ wt1,  // [A][H][128]
    u32* __restrict__ es1, u32* __restrict__ es51)
{
    int n = blockIdx.x, attr = blockIdx.y;
    int h = threadIdx.x >> 5, lane = threadIdx.x & 31;
    const float* Aattr = A + (size_t)attr*NE_;
    const float* f2p = f2 + (size_t)attr*NH*NN*16;
    float s2h = s2[attr*NH*NN + h*NN + n];
    float z[6];
    #pragma unroll
    for (int c6 = 0; c6 < 6; c6++) {
        int k = lane + 32*c6;
        float d2v = s2h * cs[attr*NN + k] + tE[attr*NH*NN + h*NN + k];
        z[c6] = fmaxf(d2v, 0.2f*d2v) + Aattr[n*NN + k];
    }
    float mx = z[0];
    #pragma unroll
    for (int c6 = 1; c6 < 6; c6++) mx = fmaxf(mx, z[c6]);
    #pragma unroll
    for (int m = 1; m < 32; m <<= 1) mx = fmaxf(mx, __shfl_xor(mx, m));
    float w[6], den = 0.f;
    #pragma unroll
    for (int c6 = 0; c6 < 6; c6++) { w[c6] = __expf(z[c6] - mx); den += w[c6]; }
    #pragma unroll
    for (int m = 1; m < 32; m <<= 1) den += __shfl_xor(den, m);
    __shared__ float attL[NH][NN];
    __shared__ float xrow[128];
    #pragma unroll
    for (int c6 = 0; c6 < 6; c6++) attL[h][lane + 32*c6] = w[c6];
    __syncthreads();
    float r = 0.f;
    if (lane < F) {
        for (int k = 0; k < NN; k++) r += attL[h][k] * f2p[((size_t)h*NN + k)*16 + lane];
        r = r/den + bn[attr*NH*F + h*F + lane];
        r = r > 0.f ? r : __expf(r) - 1.f;   // elu
        out[((size_t)n*NBA + attr)*OUTC + (LAYER == 0 ? 10 : 138) + h*F + lane] = r;
        if (LAYER == 0) {
            xh1[(size_t)attr*NN*128 + n*128 + h*16 + lane] = r;
            xrow[h*16 + lane] = r;
        }
    }
    if (LAYER == 0 && h == 7) {
        #pragma unroll
        for (int c6 = 0; c6 < 6; c6++)
            einfo[(size_t)attr*NE_ + n*NN + lane + 32*c6] = w[c6] / den;
    }
    if (LAYER == 0 && h == 0 && lane < ND)
        out[((size_t)n*NBA + attr)*OUTC + lane] = X[n*ND + lane];
    if (LAYER == 0) {
        __syncthreads();
        float sp = 0.f;
        const float* wp = wt1 + ((size_t)attr*NH + h)*128;
        #pragma unroll
        for (int q = 0; q < 4; q++) sp += xrow[lane*4+q] * wp[lane*4+q];
        #pragma unroll
        for (int m = 1; m < 32; m <<= 1) sp += __shfl_xor(sp, m);
        if (lane == 0) {
            es1 [(attr*NH + h)*NN + n] = packh(__expf(sp), __expf(sp));
            es51[(attr*NH + h)*NN + n] = packh(__expf(0.2f*sp), __expf(0.2f*sp));
        }
    }
}

extern "C" void kernel_launch(void* const* d_in, const int* in_sizes, int n_in,
                              void* d_out, int out_size, void* d_ws, size_t ws_size,
                              hipStream_t stream) {
    const float* X    = (const float*)d_in[0];
    const float* A    = (const float*)d_in[1];
    const float* E    = (const float*)d_in[2];
    const float* adj  = (const float*)d_in[3];
    const float* w_n0 = (const float*)d_in[4];
    const float* b_n0 = (const float*)d_in[5];
    const float* as0  = (const float*)d_in[6];
    const float* an0  = (const float*)d_in[7];
    const float* w_n1 = (const float*)d_in[8];
    const float* b_n1 = (const float*)d_in[9];
    const float* as1  = (const float*)d_in[10];
    const float* an1  = (const float*)d_in[11];
    const float* w_e0 = (const float*)d_in[12];
    const float* b_e0 = (const float*)d_in[13];
    const float* w_ct0= (const float*)d_in[14];
    const float* b_ct0= (const float*)d_in[15];
    const float* aes0 = (const float*)d_in[16];
    const float* aen0 = (const float*)d_in[17];
    const float* w_e1 = (const float*)d_in[18];
    const float* b_e1 = (const float*)d_in[19];
    const float* w_ct1= (const float*)d_in[20];
    const float* b_ct1= (const float*)d_in[21];
    const float* aes1 = (const float*)d_in[22];
    const float* aen1 = (const float*)d_in[23];

    float* w      = (float*)d_ws;
    u32* et0P  = (u32*)(w + OFF_ET0P);
    u32* et50P = (u32*)(w + OFF_ET50P);
    u32* et1P  = (u32*)(w + OFF_ET1P);
    u32* et51P = (u32*)(w + OFF_ET51P);
    u32* ft0P  = (u32*)(w + OFF_FT0P);
    u32* ft1P  = (u32*)(w + OFF_FT1P);
    u32* eaP   = (u32*)(w + OFF_EAP);
    float* xh1   = w + OFF_XH1;
    float* einfo = w + OFF_EINF;
    u32* es0   = (u32*)(w + OFF_ES0);
    u32* es50  = (u32*)(w + OFF_ES50);
    u32* es1   = (u32*)(w + OFF_ES1);
    u32* es51  = (u32*)(w + OFF_ES51);
    float* wt1   = w + OFF_WT1;
    float* part  = w + OFF_PART;
    float* f2    = w + OFF_F2;
    float* s2    = w + OFF_S2;
    float* t2    = w + OFF_T2;
    float* tE    = w + OFF_TE;
    float* cs    = w + OFF_CS;
    float* out   = (float*)d_out;

    k_pre<<<dim3(1825), dim3(256), 0, stream>>>(
        E, adj, X, w_e0, aen0, w_e1, aen1, w_n0, aes0, w_n1, aes1,
        et0P, et50P, et1P, et51P, ft0P, ft1P, eaP, es0, es50, wt1);

    // ---- layer 0 ----
    k_att3<4><<<dim3(64,12), dim3(512), 0, stream>>>(
        es0, es50, et0P, et50P, ft0P, eaP, part);
    k_mid<10,16,4><<<dim3(NN,NBA), dim3(256), 0, stream>>>(
        X, 0, w_n0, b_e0, w_ct0, b_ct0, as0, an0, part, f2, s2, t2);
    k_te<<<dim3(8,NBA), dim3(192), 0, stream>>>(E, (size_t)NE_, t2, tE, cs);
    k_out<16,0><<<dim3(NN,NBA), dim3(256), 0, stream>>>(
        A, s2, tE, cs, f2, b_n0, X, out, xh1, einfo, wt1, es1, es51);

    // ---- layer 1 ----
    k_att3<2><<<dim3(64,12), dim3(512), 0, stream>>>(
        es1, es51, et1P, et51P, ft1P, eaP, part);
    k_mid<128,8,2><<<dim3(NN,NBA), dim3(256), 0, stream>>>(
        xh1, NN*128, w_n1, b_e1, w_ct1, b_ct1, as1, an1, part, f2, s2, t2);
    k_te<<<dim3(8,NBA), dim3(192), 0, stream>>>(einfo, (size_t)NE_, t2, tE, cs);
    k_out<8,1><<<dim3(NN,NBA), dim3(256), 0, stream>>>(
        A, s2, tE, cs, f2, b_n1, X, out, xh1, einfo, wt1, es1, es51);
}

// Round 10
// 110.652 us; speedup vs baseline: 4.9590x; 1.1662x over previous
//
#include <hip/hip_runtime.h>
#include <hip/hip_bf16.h>

#define NN 192
#define NBA 3
#define NH 8
#define ND 10
#define NE_ (NN*NN)          // 36864
#define NE2 (NE_/2)          // 18432
#define OUTC 202             // 10 + 8*16 + 8*8

typedef unsigned int u32;
typedef unsigned short u16;
typedef __attribute__((ext_vector_type(2))) _Float16 h2v;
typedef __attribute__((ext_vector_type(8))) _Float16 f16x8;
typedef __attribute__((ext_vector_type(4))) float f32x4;

// ---- workspace layout (float-sized slots) ----
static const size_t OFF_ET0P  = 0;                        // [8][NE2] u32 half2 (et pairs)
static const size_t OFF_ET50P = OFF_ET0P  + 147456;
static const size_t OFF_ET1P  = OFF_ET50P + 147456;
static const size_t OFF_ET51P = OFF_ET1P  + 147456;
static const size_t OFF_FT0P  = OFF_ET51P + 147456;       // [8][4][NE2] u32 half2
static const size_t OFF_FT1P  = OFF_FT0P  + 589824;       // [8][2][NE2]
static const size_t OFF_EAP   = OFF_FT1P  + 294912;       // [192][NE2] u32 half2 exp(adj)
static const size_t OFF_XH1   = OFF_EAP   + 3538944;      // [3][192][128] f32
static const size_t OFF_EINF  = OFF_XH1   + 73728;        // [3][192][192]
static const size_t OFF_ES0   = OFF_EINF  + 110592;       // [3][8][192] u32 half2(es,es)
static const size_t OFF_ES50  = OFF_ES0   + 4608;
static const size_t OFF_ES1   = OFF_ES50  + 4608;
static const size_t OFF_ES51  = OFF_ES1   + 4608;
static const size_t OFF_WT1   = OFF_ES51  + 4608;         // [3][8][128] f32
static const size_t OFF_PART  = OFF_WT1   + 3072;         // [3][64][12][8][FE+1][16]
static const size_t OFF_RED   = OFF_PART  + 1474560;      // [3][96][80] reduced partials
static const size_t OFF_F2    = OFF_RED   + 23040;        // [3][8][192][16]
static const size_t OFF_S2    = OFF_F2    + 73728;
static const size_t OFF_T2    = OFF_S2    + 4608;
static const size_t OFF_TE    = OFF_T2    + 4608;
static const size_t OFF_CS    = OFF_TE    + 4608;         // [3][192]
// total ~6.82M floats ~27.3 MB

__device__ __forceinline__ u32 h2u(h2v h) { union { h2v h; u32 u; } c; c.h = h; return c.u; }
__device__ __forceinline__ h2v u2h(u32 u) { union { u32 u; h2v h; } c; c.u = u; return c.h; }
__device__ __forceinline__ u32 packh(float a, float b) {
    h2v h; h.x = (_Float16)a; h.y = (_Float16)b; return h2u(h);
}

// ---------------- K_PRE: all attr-independent preprocessing, one launch ----------------
__global__ __launch_bounds__(256) void k_pre(
    const float* __restrict__ E, const float* __restrict__ adj,
    const float* __restrict__ X,
    const float* __restrict__ we0, const float* __restrict__ aen0,
    const float* __restrict__ we1, const float* __restrict__ aen1,
    const float* __restrict__ wn0, const float* __restrict__ aes0,
    const float* __restrict__ wn1, const float* __restrict__ aes1,
    u32* __restrict__ et0P, u32* __restrict__ et50P,
    u32* __restrict__ et1P, u32* __restrict__ et51P,
    u32* __restrict__ ft0P, u32* __restrict__ ft1P,
    u32* __restrict__ eaP,
    u32* __restrict__ es0, u32* __restrict__ es50,
    float* __restrict__ wt1)
{
    int b = blockIdx.x, tid = threadIdx.x;
    if (b < 72) {
        __shared__ float w0s[96], a0s[32], w1s[512], a1s[16];
        for (int i = tid; i < 96;  i += 256) w0s[i] = we0[i];
        for (int i = tid; i < 32;  i += 256) a0s[i] = aen0[i];
        for (int i = tid; i < 512; i += 256) w1s[i] = we1[i];
        for (int i = tid; i < 16;  i += 256) a1s[i] = aen1[i];
        __syncthreads();
        int ep = b*256 + tid;            // e-pair index
        int e0 = 2*ep;
        float2 E0 = *(const float2*)(E + e0);
        float2 E1 = *(const float2*)(E + NE_ + e0);
        float2 E2 = *(const float2*)(E + 2*NE_ + e0);
        float fa[32], fb[32];
        #pragma unroll
        for (int h = 0; h < 8; h++) {
            float ta = 0.f, tb = 0.f;
            #pragma unroll
            for (int f = 0; f < 4; f++) {
                float wa = w0s[h*12+f], wb = w0s[h*12+4+f], wc = w0s[h*12+8+f];
                float va = E0.x*wa + E1.x*wb + E2.x*wc;
                float vb = E0.y*wa + E1.y*wb + E2.y*wc;
                fa[h*4+f] = va; fb[h*4+f] = vb;
                ft0P[(size_t)(h*4+f)*NE2 + ep] = packh(va, vb);
                ta += va * a0s[h*4+f];
                tb += vb * a0s[h*4+f];
            }
            et0P [h*NE2 + ep] = packh(__expf(ta), __expf(tb));
            et50P[h*NE2 + ep] = packh(__expf(0.2f*ta), __expf(0.2f*tb));
        }
        #pragma unroll
        for (int h = 0; h < 8; h++) {
            float aa = 0.f, ba = 0.f, ab = 0.f, bb = 0.f;
            #pragma unroll
            for (int d = 0; d < 32; d++) {
                float w0 = w1s[(h*32+d)*2], w1 = w1s[(h*32+d)*2+1];
                aa += fa[d] * w0;  ba += fa[d] * w1;
                ab += fb[d] * w0;  bb += fb[d] * w1;
            }
            ft1P[(size_t)(h*2+0)*NE2 + ep] = packh(aa, ab);
            ft1P[(size_t)(h*2+1)*NE2 + ep] = packh(ba, bb);
            float ta = aa*a1s[h*2] + ba*a1s[h*2+1];
            float tb = ab*a1s[h*2] + bb*a1s[h*2+1];
            et1P [h*NE2 + ep] = packh(__expf(ta), __expf(tb));
            et51P[h*NE2 + ep] = packh(__expf(0.2f*ta), __expf(0.2f*tb));
        }
    } else if (b < 1800) {
        int idx = (b - 72)*256 + tid;      // [0, 442368)
        int n = idx / 2304, c8 = idx % 2304;
        const float* ap = adj + (size_t)n*NE_ + c8*16;
        u32 o[8];
        #pragma unroll
        for (int q = 0; q < 4; q++) {
            float4 v = *(const float4*)(ap + q*4);
            o[2*q]   = packh(__expf(v.x), __expf(v.y));
            o[2*q+1] = packh(__expf(v.z), __expf(v.w));
        }
        u32* dst = eaP + (size_t)n*NE2 + c8*8;
        *(uint4*)(dst)     = make_uint4(o[0], o[1], o[2], o[3]);
        *(uint4*)(dst + 4) = make_uint4(o[4], o[5], o[6], o[7]);
    } else if (b == 1800) {
        for (int v = tid; v < 3072; v += 256) {
            int a = v >> 10, rem = v & 1023, h = rem >> 7, d = rem & 127;
            float w = 0.f;
            #pragma unroll
            for (int f = 0; f < 8; f++)
                w += wn1[(((size_t)a*NH + h)*128 + d)*8 + f] * aes1[h*8 + f];
            wt1[v] = w;
        }
    } else {
        int ah = b - 1801;
        int a = ah / NH, h = ah % NH;
        __shared__ float wt0[ND];
        if (tid < ND) {
            float w = 0.f;
            #pragma unroll
            for (int f = 0; f < 16; f++)
                w += wn0[(((size_t)a*NH + h)*ND + tid)*16 + f] * aes0[h*16 + f];
            wt0[tid] = w;
        }
        __syncthreads();
        if (tid < NN) {
            float s = 0.f;
            #pragma unroll
            for (int d = 0; d < ND; d++) s += X[tid*ND + d] * wt0[d];
            es0 [ah*NN + tid] = packh(__expf(s), __expf(s));
            es50[ah*NN + tid] = packh(__expf(0.2f*s), __expf(0.2f*s));
        }
    }
}

// ---------------- K1: e2n attention, fp16 pk-math + f16 MFMA + LDS-staged ea ----------------
// wave = head; lane (fr=lane&15 -> n-row, kg=lane>>4 -> k-group). A[n][e], B[f][e].
// ea chunk [16 n][576 e] staged in LDS once per block, shared by all 8 head-waves
// (was 8x redundant L2 reads). Row pad +4 u32 -> conflict-optimal b128 reads.
template<int FE>
__global__ __launch_bounds__(512, 3) void k_att3(
    const u32* __restrict__ es_,   // [A][H][N] half2(es,es)
    const u32* __restrict__ es5_,  // [A][H][N]
    const u32* __restrict__ etP,   // [H][NE2]
    const u32* __restrict__ et5P,  // [H][NE2]
    const u32* __restrict__ feP,   // [H][FE][NE2]
    const u32* __restrict__ eaP,   // [N][NE2]
    float* __restrict__ part)      // [A][S][12][H][FE+1][16]
{
    constexpr int S = 64, EPB = NE_/S, TILES = EPB/32;   // EPB=576, TILES=18
    constexpr int EP2 = EPB/2;                            // 288 u32 per row
    constexpr int ROWP = EP2 + 4;                         // padded row
    constexpr size_t PA = (size_t)S*12*NH*(FE+1)*16;
    __shared__ u32 sea[16*ROWP];                          // 18.7 KB

    int h = threadIdx.x >> 6, lane = threadIdx.x & 63;
    int fr = lane & 15, kg = lane >> 4;
    int split = blockIdx.x, ntile = blockIdx.y;
    int nm = ntile*16 + fr;
    int p0 = split*EP2;

    // cooperative stage: 512 threads, 16 rows x 288 u32
    {
        int r = threadIdx.x >> 5, c0 = threadIdx.x & 31;
        const u32* src = eaP + (size_t)(ntile*16 + r)*NE2 + p0;
        #pragma unroll
        for (int i = 0; i < 9; i++)
            sea[r*ROWP + c0 + i*32] = src[c0 + i*32];
    }

    h2v esh[NBA], es5h[NBA];
    #pragma unroll
    for (int a = 0; a < NBA; a++) {
        esh[a]  = u2h(es_ [(a*NH + h)*NN + nm]);
        es5h[a] = u2h(es5_[(a*NH + h)*NN + nm]);
    }

    const u32* etp  = etP  + (size_t)h*NE2 + p0 + kg*4;
    const u32* et5p = et5P + (size_t)h*NE2 + p0 + kg*4;
    const u32* fp   = feP  + ((size_t)h*FE + (fr < FE ? fr : 0))*NE2 + p0 + kg*4;
    u32 bfill = (fr == FE) ? 0x3C003C00u : 0u;   // fp16 1.0 pair / 0
    uint4 bc = make_uint4(bfill, bfill, bfill, bfill);

    f32x4 acc[NBA];
    #pragma unroll
    for (int a = 0; a < NBA; a++) acc[a] = (f32x4){0.f, 0.f, 0.f, 0.f};

    __syncthreads();

    const u32* seap = sea + fr*ROWP + kg*4;
    #pragma unroll 2
    for (int t = 0; t < TILES; t++) {
        uint4 etq  = *(const uint4*)(etp  + t*16);
        uint4 et5q = *(const uint4*)(et5p + t*16);
        uint4 eaq  = *(const uint4*)(seap + t*16);
        uint4 bq = bc;
        if (fr < FE) bq = *(const uint4*)(fp + t*16);
        union { uint4 u; f16x8 v; } B; B.u = bq;

        u32 etw[4]  = {etq.x,  etq.y,  etq.z,  etq.w};
        u32 et5w[4] = {et5q.x, et5q.y, et5q.z, et5q.w};
        u32 eaw[4]  = {eaq.x,  eaq.y,  eaq.z,  eaq.w};
        h2v g1[4], g2[4];
        #pragma unroll
        for (int p = 0; p < 4; p++) {
            h2v ea = u2h(eaw[p]);
            g1[p] = u2h(etw[p])  * ea;
            g2[p] = u2h(et5w[p]) * ea;
        }
        #pragma unroll
        for (int a = 0; a < NBA; a++) {
            union { uint4 u; f16x8 v; } A;
            u32 aw[4];
            #pragma unroll
            for (int p = 0; p < 4; p++) {
                h2v wv = __builtin_elementwise_max(esh[a] * g1[p], es5h[a] * g2[p]);
                aw[p] = h2u(wv);
            }
            A.u = make_uint4(aw[0], aw[1], aw[2], aw[3]);
            acc[a] = __builtin_amdgcn_mfma_f32_16x16x32_f16(A.v, B.v, acc[a], 0, 0, 0);
        }
    }

    if (fr <= FE) {
        float* pp = part + ((((size_t)split*12 + ntile)*NH + h)*(FE+1) + fr)*16 + kg*4;
        #pragma unroll
        for (int a = 0; a < NBA; a++)
            *(f32x4*)(pp + (size_t)a*PA) = acc[a];
    }
}

// ---------------- K1b: coalesced reduction of part over S ----------------
// grid (96) = (nt, h); threads cover (a, i) with i in [0, (FE+1)*16).
template<int FE>
__global__ __launch_bounds__(256) void k_red(
    const float* __restrict__ part, float* __restrict__ red)
{
    constexpr int S = 64, W = (FE+1)*16;
    constexpr size_t SSTR = (size_t)12*NH*W;
    constexpr size_t PA = (size_t)S*SSTR;
    int nt = blockIdx.x >> 3, h = blockIdx.x & 7;
    int t = threadIdx.x;
    if (t >= NBA*W) return;
    int a = t / W, i = t % W;
    const float* pp = part + (size_t)a*PA + ((size_t)nt*NH + h)*W + i;
    float v = 0.f;
    #pragma unroll 8
    for (int s = 0; s < S; s++) v += pp[(size_t)s*SSTR];
    red[((size_t)a*96 + nt*8 + h)*W + i] = v;
}

// ---------------- K2: f2, s2, t2 from reduced partials (grid.y = attr) ----------------
template<int DIN, int F, int FE>
__global__ __launch_bounds__(256) void k_mid(
    const float* __restrict__ Xh, int xstride,
    const float* __restrict__ wn,   // [A][H][DIN][F]
    const float* __restrict__ be,   // [H][FE]
    const float* __restrict__ wct,  // [H][F+FE][F]
    const float* __restrict__ bct,  // [H][F]
    const float* __restrict__ asf,  // [A][H][F]
    const float* __restrict__ anf,  // [A][H][F]
    const float* __restrict__ red,  // [A][96][(FE+1)*16]
    float* __restrict__ f2, float* __restrict__ s2, float* __restrict__ t2)
{
    constexpr int DCT = F + FE, W = (FE+1)*16;
    int n = blockIdx.x, attr = blockIdx.y;
    int h = threadIdx.x >> 5, lane = threadIdx.x & 31;
    const float* Xp = Xh + (size_t)attr*xstride;
    const float* wnp = wn + (size_t)attr*NH*DIN*F;
    float* f2p = f2 + (size_t)attr*NH*NN*16;
    float v = 0.f;
    if (lane <= FE)
        v = red[((size_t)attr*96 + (n>>4)*8 + h)*W + lane*16 + (n & 15)];
    float den = __shfl(v, FE, 32);
    float nfe = (lane < FE) ? v/den + be[h*FE+lane] : 0.f;
    float fv = 0.f;
    if (lane < F) {
        for (int d = 0; d < DIN; d++) fv += Xp[n*DIN+d] * wnp[(h*DIN+d)*F+lane];
    }
    __shared__ float c[NH][DCT];
    if (lane < F)  c[h][lane]     = fv;
    if (lane < FE) c[h][F + lane] = nfe;
    __syncthreads();
    float f2v = 0.f;
    if (lane < F) {
        f2v = bct[h*F+lane];
        #pragma unroll
        for (int d = 0; d < DCT; d++) f2v += c[h][d] * wct[(h*DCT+d)*F+lane];
        f2p[((size_t)h*NN + n)*16 + lane] = f2v;
    }
    float s2p = (lane < F) ? f2v * asf[attr*NH*F + h*F+lane] : 0.f;
    float t2p = (lane < F) ? f2v * anf[attr*NH*F + h*F+lane] : 0.f;
    #pragma unroll
    for (int m = 1; m < 32; m <<= 1) { s2p += __shfl_xor(s2p, m); t2p += __shfl_xor(t2p, m); }
    if (lane == 0) { s2[attr*NH*NN + h*NN+n] = s2p; t2[attr*NH*NN + h*NN+n] = t2p; }
}

// ---------------- K3: tE[h,k] = sum_m t2[h,m]*Einfo[m,k]; colsum (grid.y=attr) ----------------
__global__ __launch_bounds__(192) void k_te(
    const float* __restrict__ Einfo, size_t estride,
    const float* __restrict__ t2,
    float* __restrict__ tE, float* __restrict__ cs)
{
    int h = blockIdx.x, attr = blockIdx.y, k = threadIdx.x;
    const float* Ep = Einfo + (size_t)attr*estride;
    float a = 0.f, c = 0.f;
    for (int m = 0; m < NN; m++) {
        float ev = Ep[m*NN + k];
        a += t2[attr*NH*NN + h*NN + m] * ev;
        c += ev;
    }
    tE[attr*NH*NN + h*NN + k] = a;
    if (h == 0) cs[attr*NN + k] = c;
}

// ---------------- K4: att2 rows, nf, outputs (grid.y = attr); L0 also emits es1 ----------------
template<int F, int LAYER>
__global__ __launch_bounds__(256) void k_out(
    const float* __restrict__ A,    // [A][N][N]
    const float* __restrict__ s2, const float* __restrict__ tE,
    const float* __restrict__ cs, const float* __restrict__ f2,
    const float* __restrict__ bn,   // [A][H][F]
    const float* __restrict__ X,
    float* __restrict__ out,
    float* __restrict__ xh1, float* __restrict__ einfo,
    const float* __restrict__ wt1,  // [A][H][128]
    u32* __restrict__ es1, u32* __restrict__ es51)
{
    int n = blockIdx.x, attr = blockIdx.y;
    int h = threadIdx.x >> 5, lane = threadIdx.x & 31;
    const float* Aattr = A + (size_t)attr*NE_;
    const float* f2p = f2 + (size_t)attr*NH*NN*16;
    float s2h = s2[attr*NH*NN + h*NN + n];
    float z[6];
    #pragma unroll
    for (int c6 = 0; c6 < 6; c6++) {
        int k = lane + 32*c6;
        float d2v = s2h * cs[attr*NN + k] + tE[attr*NH*NN + h*NN + k];
        z[c6] = fmaxf(d2v, 0.2f*d2v) + Aattr[n*NN + k];
    }
    float mx = z[0];
    #pragma unroll
    for (int c6 = 1; c6 < 6; c6++) mx = fmaxf(mx, z[c6]);
    #pragma unroll
    for (int m = 1; m < 32; m <<= 1) mx = fmaxf(mx, __shfl_xor(mx, m));
    float w[6], den = 0.f;
    #pragma unroll
    for (int c6 = 0; c6 < 6; c6++) { w[c6] = __expf(z[c6] - mx); den += w[c6]; }
    #pragma unroll
    for (int m = 1; m < 32; m <<= 1) den += __shfl_xor(den, m);
    __shared__ float attL[NH][NN];
    __shared__ float xrow[128];
    #pragma unroll
    for (int c6 = 0; c6 < 6; c6++) attL[h][lane + 32*c6] = w[c6];
    __syncthreads();
    float r = 0.f;
    if (lane < F) {
        for (int k = 0; k < NN; k++) r += attL[h][k] * f2p[((size_t)h*NN + k)*16 + lane];
        r = r/den + bn[attr*NH*F + h*F + lane];
        r = r > 0.f ? r : __expf(r) - 1.f;   // elu
        out[((size_t)n*NBA + attr)*OUTC + (LAYER == 0 ? 10 : 138) + h*F + lane] = r;
        if (LAYER == 0) {
            xh1[(size_t)attr*NN*128 + n*128 + h*16 + lane] = r;
            xrow[h*16 + lane] = r;
        }
    }
    if (LAYER == 0 && h == 7) {
        #pragma unroll
        for (int c6 = 0; c6 < 6; c6++)
            einfo[(size_t)attr*NE_ + n*NN + lane + 32*c6] = w[c6] / den;
    }
    if (LAYER == 0 && h == 0 && lane < ND)
        out[((size_t)n*NBA + attr)*OUTC + lane] = X[n*ND + lane];
    if (LAYER == 0) {
        __syncthreads();
        float sp = 0.f;
        const float* wp = wt1 + ((size_t)attr*NH + h)*128;
        #pragma unroll
        for (int q = 0; q < 4; q++) sp += xrow[lane*4+q] * wp[lane*4+q];
        #pragma unroll
        for (int m = 1; m < 32; m <<= 1) sp += __shfl_xor(sp, m);
        if (lane == 0) {
            es1 [(attr*NH + h)*NN + n] = packh(__expf(sp), __expf(sp));
            es51[(attr*NH + h)*NN + n] = packh(__expf(0.2f*sp), __expf(0.2f*sp));
        }
    }
}

extern "C" void kernel_launch(void* const* d_in, const int* in_sizes, int n_in,
                              void* d_out, int out_size, void* d_ws, size_t ws_size,
                              hipStream_t stream) {
    const float* X    = (const float*)d_in[0];
    const float* A    = (const float*)d_in[1];
    const float* E    = (const float*)d_in[2];
    const float* adj  = (const float*)d_in[3];
    const float* w_n0 = (const float*)d_in[4];
    const float* b_n0 = (const float*)d_in[5];
    const float* as0  = (const float*)d_in[6];
    const float* an0  = (const float*)d_in[7];
    const float* w_n1 = (const float*)d_in[8];
    const float* b_n1 = (const float*)d_in[9];
    const float* as1  = (const float*)d_in[10];
    const float* an1  = (const float*)d_in[11];
    const float* w_e0 = (const float*)d_in[12];
    const float* b_e0 = (const float*)d_in[13];
    const float* w_ct0= (const float*)d_in[14];
    const float* b_ct0= (const float*)d_in[15];
    const float* aes0 = (const float*)d_in[16];
    const float* aen0 = (const float*)d_in[17];
    const float* w_e1 = (const float*)d_in[18];
    const float* b_e1 = (const float*)d_in[19];
    const float* w_ct1= (const float*)d_in[20];
    const float* b_ct1= (const float*)d_in[21];
    const float* aes1 = (const float*)d_in[22];
    const float* aen1 = (const float*)d_in[23];

    float* w      = (float*)d_ws;
    u32* et0P  = (u32*)(w + OFF_ET0P);
    u32* et50P = (u32*)(w + OFF_ET50P);
    u32* et1P  = (u32*)(w + OFF_ET1P);
    u32* et51P = (u32*)(w + OFF_ET51P);
    u32* ft0P  = (u32*)(w + OFF_FT0P);
    u32* ft1P  = (u32*)(w + OFF_FT1P);
    u32* eaP   = (u32*)(w + OFF_EAP);
    float* xh1   = w + OFF_XH1;
    float* einfo = w + OFF_EINF;
    u32* es0   = (u32*)(w + OFF_ES0);
    u32* es50  = (u32*)(w + OFF_ES50);
    u32* es1   = (u32*)(w + OFF_ES1);
    u32* es51  = (u32*)(w + OFF_ES51);
    float* wt1   = w + OFF_WT1;
    float* part  = w + OFF_PART;
    float* red   = w + OFF_RED;
    float* f2    = w + OFF_F2;
    float* s2    = w + OFF_S2;
    float* t2    = w + OFF_T2;
    float* tE    = w + OFF_TE;
    float* cs    = w + OFF_CS;
    float* out   = (float*)d_out;

    k_pre<<<dim3(1825), dim3(256), 0, stream>>>(
        E, adj, X, w_e0, aen0, w_e1, aen1, w_n0, aes0, w_n1, aes1,
        et0P, et50P, et1P, et51P, ft0P, ft1P, eaP, es0, es50, wt1);

    // ---- layer 0 ----
    k_att3<4><<<dim3(64,12), dim3(512), 0, stream>>>(
        es0, es50, et0P, et50P, ft0P, eaP, part);
    k_red<4><<<dim3(96), dim3(256), 0, stream>>>(part, red);
    k_mid<10,16,4><<<dim3(NN,NBA), dim3(256), 0, stream>>>(
        X, 0, w_n0, b_e0, w_ct0, b_ct0, as0, an0, red, f2, s2, t2);
    k_te<<<dim3(8,NBA), dim3(192), 0, stream>>>(E, (size_t)NE_, t2, tE, cs);
    k_out<16,0><<<dim3(NN,NBA), dim3(256), 0, stream>>>(
        A, s2, tE, cs, f2, b_n0, X, out, xh1, einfo, wt1, es1, es51);

    // ---- layer 1 ----
    k_att3<2><<<dim3(64,12), dim3(512), 0, stream>>>(
        es1, es51, et1P, et51P, ft1P, eaP, part);
    k_red<2><<<dim3(96), dim3(256), 0, stream>>>(part, red);
    k_mid<128,8,2><<<dim3(NN,NBA), dim3(256), 0, stream>>>(
        xh1, NN*128, w_n1, b_e1, w_ct1, b_ct1, as1, an1, red, f2, s2, t2);
    k_te<<<dim3(8,NBA), dim3(192), 0, stream>>>(einfo, (size_t)NE_, t2, tE, cs);
    k_out<8,1><<<dim3(NN,NBA), dim3(256), 0, stream>>>(
        A, s2, tE, cs, f2, b_n1, X, out, xh1, einfo, wt1, es1, es51);
}